// Round 14
// baseline (1023.910 us; speedup 1.0000x reference)
//
#include <hip/hip_runtime.h>
#include <stdint.h>

using u32 = unsigned int;
using u64 = unsigned long long;

constexpr int BATCH = 4;
constexpr int H0 = 1080, W0 = 1920;     // input
constexpr int HP = 539,  WP = 959;      // after conv1(3x3 VALID)+pool2
constexpr int H2 = 537,  W2 = 957;      // after conv2
constexpr int H3 = 535,  W3 = 955;      // after conv3
constexpr int N3 = H3 * W3;             // 510925
constexpr int TOT3 = BATCH * N3;        // 2043700
constexpr int KSEL = 1024;
constexpr int SORTCAP = 4096;
constexpr float SCORE_THR_C = 0.6f;
constexpr float IOU_THR_C = 0.5f;
constexpr float IMG_OFF = 100000.0f;

// batched grids
constexpr int T1RY = 34, T1CX = 30;     // conv1: 16x32 pooled tile
constexpr int C2TY = 34, C2TX = 30;     // conv2: 16x32 tile
constexpr int C3TY = 34, C3TX = 30;     // conv3: 16x32 tile

// ---------------- workspace layout (bytes) ----------------
constexpr size_t align256(size_t x) { return (x + 255) & ~(size_t)255; }
constexpr size_t oP1   = 0;
constexpr size_t sP1   = (size_t)BATCH * 10 * HP * WP * 4;     // 82.7 MB
constexpr size_t oC2   = align256(oP1 + sP1);
constexpr size_t sC2   = (size_t)BATCH * 16 * H2 * W2 * 4;     // 131.5 MB
constexpr size_t oCand = align256(oC2 + sC2);
constexpr size_t sCand = (size_t)TOT3 * 8;                     // 16.3 MB
constexpr size_t oSel  = align256(oCand + sCand);
constexpr size_t oKeep = align256(oSel + (size_t)KSEL * 8);
constexpr size_t oMisc = align256(oKeep + 16 * 8);
constexpr int    MISC_WORDS = 16 + 2048;   // [0]=cand_count ; +16: hist[2048]
constexpr size_t WS_NEEDED = oMisc + (size_t)MISC_WORDS * 4;

__device__ __forceinline__ int keybin(u64 key) {
  u32 khi = (u32)(key >> 32);
  int d = (int)(khi - 0xC0800000u);   // scores in [0.5,1) land in [0, 0x800000)
  if (d < 0) d = 0;
  int bin = d >> 12;
  return bin > 2047 ? 2047 : bin;
}

// ---------------- conv1 + PReLU + 2x2 maxpool : LDS-tiled 16x32 pooled tile, 2 px/thread ----------------
__global__ __launch_bounds__(256) void k_conv1(
    const float* __restrict__ x, const float* __restrict__ w1,
    const float* __restrict__ b1, const float* __restrict__ a1,
    float* __restrict__ P1, u32* __restrict__ misc) {
  __shared__ float sm[6834];
  int tid = threadIdx.x;
  int blk = blockIdx.x;
  if (blk == 0) {
    for (int i = tid; i < MISC_WORDS; i += 256) misc[i] = 0;
  }
  int btx = blk % T1CX; int r1 = blk / T1CX; int bty = r1 % T1RY; int b = r1 / T1RY;
  int r0 = 16 * bty; if (r0 > 523) r0 = 523;   // clamp; overlap recompute idempotent
  int c0 = 32 * btx; if (c0 > 927) c0 = 927;

  const float* xb = x + (size_t)b * 3 * H0 * W0;
  for (int i = tid; i < 6732; i += 256) {
    int ci = i / 2244; int rem = i - ci * 2244; int row = rem / 66; int col = rem - row * 66;
    sm[ci * 2278 + row * 67 + col] =
        xb[(size_t)ci * H0 * W0 + (size_t)(2 * r0 + row) * W0 + (2 * c0 + col)];
  }
  __syncthreads();

  int pr = tid >> 4, pc = tid & 15;
  float acc[10][8];
  #pragma unroll
  for (int c = 0; c < 10; ++c) {
    float bb = b1[c];
    #pragma unroll
    for (int o = 0; o < 8; ++o) acc[c][o] = bb;
  }
  #pragma unroll 1
  for (int ci = 0; ci < 3; ++ci) {
    const float* sp = sm + ci * 2278 + (2 * pr) * 67 + 4 * pc;
    float in[4][6];
    #pragma unroll
    for (int iy = 0; iy < 4; ++iy)
      #pragma unroll
      for (int ix = 0; ix < 6; ++ix)
        in[iy][ix] = sp[iy * 67 + ix];
    #pragma unroll
    for (int c = 0; c < 10; ++c) {
      const float* wc = w1 + (c * 3 + ci) * 9;
      float w0v = wc[0], w1v = wc[1], w2v = wc[2], w3v = wc[3], w4v = wc[4],
            w5v = wc[5], w6v = wc[6], w7v = wc[7], w8v = wc[8];
      #pragma unroll
      for (int sr = 0; sr < 2; ++sr)
        #pragma unroll
        for (int sc = 0; sc < 4; ++sc) {
          float a = acc[c][sr * 4 + sc];
          a = fmaf(in[sr][sc],     w0v, a); a = fmaf(in[sr][sc+1],   w1v, a); a = fmaf(in[sr][sc+2],   w2v, a);
          a = fmaf(in[sr+1][sc],   w3v, a); a = fmaf(in[sr+1][sc+1], w4v, a); a = fmaf(in[sr+1][sc+2], w5v, a);
          a = fmaf(in[sr+2][sc],   w6v, a); a = fmaf(in[sr+2][sc+1], w7v, a); a = fmaf(in[sr+2][sc+2], w8v, a);
          acc[c][sr * 4 + sc] = a;
        }
    }
  }
  int gy = r0 + pr, gx = c0 + 2 * pc;
  size_t base = ((size_t)(b * 10) * HP + gy) * WP + gx;
  #pragma unroll
  for (int c = 0; c < 10; ++c) {
    float al = a1[c];
    float v[8];
    #pragma unroll
    for (int o = 0; o < 8; ++o) { float u = acc[c][o]; v[o] = u >= 0.0f ? u : al * u; }
    float m0 = fmaxf(fmaxf(v[0], v[1]), fmaxf(v[4], v[5]));
    float m1 = fmaxf(fmaxf(v[2], v[3]), fmaxf(v[6], v[7]));
    P1[base + (size_t)c * HP * WP]     = m0;
    P1[base + (size_t)c * HP * WP + 1] = m1;
  }
}

// ---------------- conv2 + PReLU : 16x32 tile, 4 waves x 4 ch, 8 px/thread ----------------
__global__ __launch_bounds__(256) void k_conv2(
    const float* __restrict__ P1, const float* __restrict__ w2,
    const float* __restrict__ b2, const float* __restrict__ a2,
    float* __restrict__ C2) {
  __shared__ float sm[6300];
  int tid = threadIdx.x;
  int blk = blockIdx.x;
  int tx = blk % C2TX; int r1 = blk / C2TX; int ty = r1 % C2TY; int b = r1 / C2TY;
  int r0 = 16 * ty; if (r0 > 521) r0 = 521;
  int c0 = 32 * tx; if (c0 > 925) c0 = 925;

  const float* Pb = P1 + (size_t)b * 10 * HP * WP;
  for (int i = tid; i < 6120; i += 256) {
    int ci = i / 612; int rem = i - ci * 612; int row = rem / 34; int col = rem - row * 34;
    sm[ci * 630 + row * 35 + col] =
        Pb[(size_t)ci * HP * WP + (size_t)(r0 + row) * WP + (c0 + col)];
  }
  __syncthreads();

  int lane = tid & 63;
  int wv = __builtin_amdgcn_readfirstlane(tid >> 6);
  int c_lo = wv * 4;
  int rr = lane >> 3;
  int gg = lane & 7;

  float acc[4][8];
  #pragma unroll
  for (int c = 0; c < 4; ++c) {
    float bb = b2[c_lo + c];
    #pragma unroll
    for (int o = 0; o < 8; ++o) acc[c][o] = bb;
  }
  #pragma unroll 1
  for (int ci = 0; ci < 10; ++ci) {
    const float* sp = sm + ci * 630 + (2 * rr) * 35 + 4 * gg;
    float in[4][6];
    #pragma unroll
    for (int dy = 0; dy < 4; ++dy)
      #pragma unroll
      for (int dx = 0; dx < 6; ++dx)
        in[dy][dx] = sp[dy * 35 + dx];
    #pragma unroll
    for (int c = 0; c < 4; ++c) {
      const float* wc = w2 + ((c_lo + c) * 10 + ci) * 9;
      float w0v = wc[0], w1v = wc[1], w2v = wc[2], w3v = wc[3], w4v = wc[4],
            w5v = wc[5], w6v = wc[6], w7v = wc[7], w8v = wc[8];
      #pragma unroll
      for (int d = 0; d < 2; ++d)
        #pragma unroll
        for (int k = 0; k < 4; ++k) {
          float a = acc[c][d * 4 + k];
          a = fmaf(in[d][k],   w0v, a); a = fmaf(in[d][k+1],   w1v, a); a = fmaf(in[d][k+2],   w2v, a);
          a = fmaf(in[d+1][k], w3v, a); a = fmaf(in[d+1][k+1], w4v, a); a = fmaf(in[d+1][k+2], w5v, a);
          a = fmaf(in[d+2][k], w6v, a); a = fmaf(in[d+2][k+1], w7v, a); a = fmaf(in[d+2][k+2], w8v, a);
          acc[c][d * 4 + k] = a;
        }
    }
  }
  #pragma unroll
  for (int c = 0; c < 4; ++c) {
    float al = a2[c_lo + c];
    #pragma unroll
    for (int d = 0; d < 2; ++d) {
      int gy = r0 + 2 * rr + d;
      size_t base = ((size_t)(b * 16 + c_lo + c) * H2 + gy) * W2 + (c0 + 4 * gg);
      #pragma unroll
      for (int k = 0; k < 4; ++k) {
        float v = acc[c][d * 4 + k];
        C2[base + k] = v >= 0.0f ? v : al * v;
      }
    }
  }
}

// ---------------- conv3 core (scalar 32-ch; used by k_emit only) ----------------
__device__ __forceinline__ void conv3_h(
    const float* __restrict__ C2, const float* __restrict__ w3,
    const float* __restrict__ b3, const float* __restrict__ a3,
    int b, int y, int x, float* h) {
  #pragma unroll
  for (int c = 0; c < 32; ++c) h[c] = b3[c];
  #pragma unroll 1
  for (int ci = 0; ci < 16; ++ci) {
    const float* p = C2 + ((size_t)(b * 16 + ci) * H2 + y) * W2 + x;
    float i0 = p[0],      i1 = p[1],      i2 = p[2];
    float i3 = p[W2],     i4 = p[W2+1],   i5 = p[W2+2];
    float i6 = p[2*W2],   i7 = p[2*W2+1], i8 = p[2*W2+2];
    const float* wp = w3 + ci * 9;
    #pragma unroll
    for (int c = 0; c < 32; ++c) {
      const float* wc = wp + c * 144;
      h[c] = fmaf(i0, wc[0], h[c]); h[c] = fmaf(i1, wc[1], h[c]);
      h[c] = fmaf(i2, wc[2], h[c]); h[c] = fmaf(i3, wc[3], h[c]);
      h[c] = fmaf(i4, wc[4], h[c]); h[c] = fmaf(i5, wc[5], h[c]);
      h[c] = fmaf(i6, wc[6], h[c]); h[c] = fmaf(i7, wc[7], h[c]);
      h[c] = fmaf(i8, wc[8], h[c]);
    }
  }
  #pragma unroll
  for (int c = 0; c < 32; ++c) h[c] = h[c] >= 0.0f ? h[c] : a3[c] * h[c];
}

// ---------------- conv3 + PReLU + head + filter + inline hist : tile 16x32, 4 waves x 8 ch, 8 px/thread ----------------
__global__ __launch_bounds__(256) void k_conv3(
    const float* __restrict__ C2, const float* __restrict__ w3,
    const float* __restrict__ b3, const float* __restrict__ a3,
    const float* __restrict__ w41, const float* __restrict__ b41,
    u64* __restrict__ cands, u32* __restrict__ misc) {
  __shared__ __align__(16) float sm[10080];
  int tid = threadIdx.x;
  int blk = blockIdx.x;
  int tx = blk % C3TX; int r1 = blk / C3TX; int ty = r1 % C3TY; int b = r1 / C3TY;
  int ymin = 16 * ty, xmin = 32 * tx;
  int r0 = ymin > 519 ? 519 : ymin;
  int c0 = xmin > 923 ? 923 : xmin;

  const float* Cb = C2 + (size_t)b * 16 * H2 * W2;
  for (int i = tid; i < 9792; i += 256) {
    int ci = i / 612; int rem = i - ci * 612; int row = rem / 34; int col = rem - row * 34;
    sm[ci * 630 + row * 35 + col] =
        Cb[(size_t)ci * H2 * W2 + (size_t)(r0 + row) * W2 + (c0 + col)];
  }
  __syncthreads();

  int lane = tid & 63;
  int wv = __builtin_amdgcn_readfirstlane(tid >> 6);
  int c_lo = wv * 8;
  int rr = lane >> 3;
  int gg = lane & 7;

  float acc[8][8];
  #pragma unroll
  for (int c = 0; c < 8; ++c) {
    float bb = b3[c_lo + c];
    #pragma unroll
    for (int o = 0; o < 8; ++o) acc[c][o] = bb;
  }
  #pragma unroll 1
  for (int ci = 0; ci < 16; ++ci) {
    const float* sp = sm + ci * 630 + (2 * rr) * 35 + 4 * gg;
    float in[4][6];
    #pragma unroll
    for (int dy = 0; dy < 4; ++dy)
      #pragma unroll
      for (int dx = 0; dx < 6; ++dx)
        in[dy][dx] = sp[dy * 35 + dx];
    #pragma unroll
    for (int c = 0; c < 8; ++c) {
      const float* wc = w3 + ((c_lo + c) * 16 + ci) * 9;
      float w0v = wc[0], w1v = wc[1], w2v = wc[2], w3v = wc[3], w4v = wc[4],
            w5v = wc[5], w6v = wc[6], w7v = wc[7], w8v = wc[8];
      #pragma unroll
      for (int d = 0; d < 2; ++d)
        #pragma unroll
        for (int k = 0; k < 4; ++k) {
          float a = acc[c][d * 4 + k];
          a = fmaf(in[d][k],   w0v, a); a = fmaf(in[d][k+1],   w1v, a); a = fmaf(in[d][k+2],   w2v, a);
          a = fmaf(in[d+1][k], w3v, a); a = fmaf(in[d+1][k+1], w4v, a); a = fmaf(in[d+1][k+2], w5v, a);
          a = fmaf(in[d+2][k], w6v, a); a = fmaf(in[d+2][k+1], w7v, a); a = fmaf(in[d+2][k+2], w8v, a);
          acc[c][d * 4 + k] = a;
        }
    }
  }
  #pragma unroll
  for (int c = 0; c < 8; ++c) {
    float al = a3[c_lo + c];
    #pragma unroll
    for (int o = 0; o < 8; ++o) {
      float v = acc[c][o];
      acc[c][o] = v >= 0.0f ? v : al * v;
    }
  }
  __syncthreads();

  #pragma unroll
  for (int halfp = 0; halfp < 2; ++halfp) {
    if ((rr >> 2) == halfp) {
      #pragma unroll
      for (int c = 0; c < 8; ++c)
        #pragma unroll
        for (int d = 0; d < 2; ++d) {
          int row = 2 * rr + d - 8 * halfp;
          int word = (c_lo + c) * 256 + row * 32 + 4 * gg;
          *(float4*)&sm[word] = make_float4(acc[c][d*4+0], acc[c][d*4+1], acc[c][d*4+2], acc[c][d*4+3]);
        }
    }
    __syncthreads();
    {
      int p = tid;
      float l0 = b41[0], l1 = b41[1];
      #pragma unroll
      for (int c = 0; c < 32; ++c) {
        float hv = sm[c * 256 + p];
        l0 = fmaf(hv, w41[c],      l0);
        l1 = fmaf(hv, w41[32 + c], l1);
      }
      float prob = 1.0f / (1.0f + expf(l0 - l1));
      int gy = r0 + 8 * halfp + (p >> 5);
      int gx = c0 + (p & 31);
      if (prob >= SCORE_THR_C && gy >= ymin && gx >= xmin) {
        u32 idx = (u32)(b * N3 + gy * W3 + gx);
        u64 key = ((u64)(~__float_as_uint(prob)) << 32) | idx;
        atomicAdd(&misc[16 + keybin(key)], 1u);
        u32 pos = atomicAdd(&misc[0], 1u);
        cands[pos] = key;
      }
    }
    __syncthreads();
  }
}

// ---------------- fused tail: scan+compact+sort+sup+nms, single block x 1024 threads ----------------
// LDS layout (99328 B): sbuf u64[4096] @0 (keys 0..1023 live after sort);
//   lsup u64[8192] @8192 (overlaps dead sbuf tail); lbox float4[1024] @73728;
//   lh u32[2048] @90112; part u32[256] @98304.
__global__ __launch_bounds__(1024) void k_tail(
    const u64* __restrict__ cands, u32* __restrict__ misc,
    u64* __restrict__ selected, u64* __restrict__ keep) {
  __shared__ __align__(16) char smraw[99328];
  u64*    sbuf = (u64*)smraw;
  u64*    lsup = (u64*)(smraw + 8192);
  float4* lbox = (float4*)(smraw + 73728);
  u32*    lh   = (u32*)(smraw + 90112);
  u32*    part = (u32*)(smraw + 98304);
  __shared__ u32 s_bstar, s_keff, s_cnt;
  __shared__ u64 remw[16], keepres[16];
  int tid = threadIdx.x;
  int lane = tid & 63;

  // phase 0: histogram -> bstar, keff
  for (int t = tid; t < 2048; t += 1024) lh[t] = misc[16 + t];
  if (tid == 0) s_cnt = 0;
  __syncthreads();
  if (tid < 256) {
    u32 s = 0;
    #pragma unroll
    for (int k = 0; k < 8; ++k) s += lh[tid * 8 + k];
    part[tid] = s;
  }
  __syncthreads();
  if (tid == 0) {
    u32 total = misc[0]; if (total > (u32)TOT3) total = TOT3;
    u32 keff = total < (u32)KSEL ? total : (u32)KSEL;
    u32 run = 0; int chunk = 255;
    for (int t = 0; t < 256; ++t) {
      if (run + part[t] >= keff) { chunk = t; break; }
      run += part[t];
    }
    int bstar = 2047;
    for (int b = chunk * 8; b < chunk * 8 + 8; ++b) {
      u32 hv = lh[b];
      if (run + hv >= keff) { bstar = b; break; }
      run += hv;
    }
    s_bstar = (u32)bstar;
    s_keff = keff;
  }
  __syncthreads();

  // phase 1: scan candidates, compact qualifying keys into LDS
  {
    int bstar = (int)s_bstar;
    u32 n = misc[0]; if (n > (u32)TOT3) n = TOT3;
    for (u32 i = tid; i < n; i += 1024) {
      u64 key = cands[i];
      if (keybin(key) <= bstar) {
        u32 pos = atomicAdd(&s_cnt, 1u);
        if (pos < (u32)SORTCAP) sbuf[pos] = key;
      }
    }
  }
  __syncthreads();

  // phase 2: bitonic sort (adaptive pow2 >= nsel, >= 1024)
  u32 nsel = s_cnt; if (nsel > (u32)SORTCAP) nsel = SORTCAP;
  unsigned m = KSEL;
  while (m < nsel) m <<= 1;
  for (int t = tid; t < (int)m; t += 1024) if (t >= (int)nsel) sbuf[t] = ~0ULL;
  __syncthreads();
  for (unsigned k = 2; k <= m; k <<= 1) {
    for (unsigned j = k >> 1; j > 0; j >>= 1) {
      for (int t = tid; t < (int)m; t += 1024) {
        int ixj = t ^ (int)j;
        if (ixj > t) {
          u64 a = sbuf[t], b = sbuf[ixj];
          bool up = ((t & (int)k) == 0);
          if ((a > b) == up) { sbuf[t] = b; sbuf[ixj] = a; }
        }
      }
      __syncthreads();
    }
  }

  // phase 3: selected keys -> global (for k_emit) + boxes -> LDS
  {
    u64 key = sbuf[tid];       // note: tid < 1024 = KSEL
    selected[tid] = key;
    u32 idx = (u32)key;
    u32 b = idx / (u32)N3;
    u32 rem = idx - b * (u32)N3;
    u32 y = rem / (u32)W3;
    u32 x = rem - y * (u32)W3;
    float off = (float)b * IMG_OFF;
    float x1 = (float)(2 * (int)x + 1) + off;
    float y1 = (float)(2 * (int)y + 1) + off;
    lbox[tid] = make_float4(x1, y1, x1 + 11.0f, y1 + 11.0f);
  }
  {
    int total = (int)s_keff;
    if (tid < 16) {
      remw[tid] = 0;
      int nb = total - tid * 64;
      keepres[tid] = nb >= 64 ? ~0ULL : (nb <= 0 ? 0ULL : ((1ULL << nb) - 1ULL));
    }
  }
  __syncthreads();

  // phase 4: per-chunk sup compute + block-parallel greedy nms
  for (int chunk = 0; chunk < 2; ++chunk) {
    for (int task = tid; task < 8192; task += 1024) {
      int i = task >> 4;           // row within chunk 0..511
      int w = task & 15;
      int ir = chunk * 512 + i;
      float4 bi = lbox[ir];
      float ai = (bi.z - bi.x) * (bi.w - bi.y);
      u64 msk = 0;
      #pragma unroll 4
      for (int jj = 0; jj < 64; ++jj) {
        int j = (w << 6) + jj;
        float4 bj = lbox[j];
        float xx1 = fmaxf(bi.x, bj.x), yy1 = fmaxf(bi.y, bj.y);
        float xx2 = fminf(bi.z, bj.z), yy2 = fminf(bi.w, bj.w);
        float inter = fmaxf(xx2 - xx1, 0.0f) * fmaxf(yy2 - yy1, 0.0f);
        float aj = (bj.z - bj.x) * (bj.w - bj.y);
        float iou = inter / (ai + aj - inter);
        if (iou > IOU_THR_C && j > ir) msk |= (1ULL << jj);
      }
      lsup[(size_t)i * 16 + w] = msk;
    }
    __syncthreads();
    for (int jb = 0; jb < 8; ++jb) {
      int j = chunk * 8 + jb;
      if (tid < 64) {
        u64 intra = lsup[(jb * 64 + lane) * 16 + j];
        u64 kw = keepres[j] & ~remw[j];
        #pragma unroll 8
        for (int bbit = 0; bbit < 64; ++bbit) {
          u64 row = __shfl(intra, bbit);
          if ((kw >> bbit) & 1ULL) kw &= ~row;
        }
        if (lane == 0) keepres[j] = kw;
      }
      __syncthreads();
      if (tid < 16) {
        u64 kw = keepres[j];
        u64 r = remw[tid];
        int base = jb * 64;
        while (kw) {
          int bbit = __ffsll(kw) - 1;
          kw &= kw - 1;
          r |= lsup[(base + bbit) * 16 + tid];
        }
        remw[tid] = r;
      }
      __syncthreads();
    }
  }
  if (tid < 16) keep[tid] = keepres[tid];
}

// ---------------- final emit: recompute pred head for kept rows ----------------
__global__ __launch_bounds__(256) void k_emit(
    const float* __restrict__ C2, const float* __restrict__ w3,
    const float* __restrict__ b3, const float* __restrict__ a3,
    const float* __restrict__ w42, const float* __restrict__ b42,
    const u64* __restrict__ selected, const u64* __restrict__ keep,
    float* __restrict__ out) {
  int r = blockIdx.x * 256 + threadIdx.x;
  if (r >= KSEL) return;
  bool kb = (keep[r >> 6] >> (r & 63)) & 1ULL;
  if (!kb) {
    out[r*5+0] = 0.0f; out[r*5+1] = 0.0f; out[r*5+2] = 0.0f;
    out[r*5+3] = 0.0f; out[r*5+4] = 0.0f;
    return;
  }
  u64 key = selected[r];
  float score = __uint_as_float(~(u32)(key >> 32));
  u32 idx = (u32)key;
  int b = (int)(idx / (u32)N3);
  int rem = (int)(idx - (u32)b * (u32)N3);
  int y = rem / W3;
  int x = rem - y * W3;
  float h[32];
  conv3_h(C2, w3, b3, a3, b, y, x, h);
  float p0 = b42[0], p1 = b42[1], p2 = b42[2], p3 = b42[3];
  #pragma unroll
  for (int c = 0; c < 32; ++c) {
    p0 = fmaf(h[c], w42[c],      p0);
    p1 = fmaf(h[c], w42[32 + c], p1);
    p2 = fmaf(h[c], w42[64 + c], p2);
    p3 = fmaf(h[c], w42[96 + c], p3);
  }
  float x1 = (float)(2 * x + 1), y1f = (float)(2 * y + 1);
  float x2 = (float)(2 * x + 12), y2f = (float)(2 * y + 12);
  float bw = x2 - x1, bh = y2f - y1f;
  float rx1 = fmaf(p0, bw, x1), ry1 = fmaf(p1, bh, y1f);
  float rx2 = fmaf(p2, bw, x2), ry2 = fmaf(p3, bh, y2f);
  float rw = rx2 - rx1, rh = ry2 - ry1;
  float l = fmaxf(rw, rh);
  float ox1 = rx1 + 0.5f * rw - 0.5f * l;
  float oy1 = ry1 + 0.5f * rh - 0.5f * l;
  out[r*5+0] = ox1; out[r*5+1] = oy1;
  out[r*5+2] = ox1 + l; out[r*5+3] = oy1 + l;
  out[r*5+4] = score;
}

extern "C" void kernel_launch(void* const* d_in, const int* in_sizes, int n_in,
                              void* d_out, int out_size, void* d_ws, size_t ws_size,
                              hipStream_t stream) {
  if (ws_size < WS_NEEDED) return;
  const float* x   = (const float*)d_in[0];
  const float* w1  = (const float*)d_in[1];
  const float* b1  = (const float*)d_in[2];
  const float* a1  = (const float*)d_in[3];
  const float* w2  = (const float*)d_in[4];
  const float* b2  = (const float*)d_in[5];
  const float* a2  = (const float*)d_in[6];
  const float* w3  = (const float*)d_in[7];
  const float* b3  = (const float*)d_in[8];
  const float* a3  = (const float*)d_in[9];
  const float* w41 = (const float*)d_in[10];
  const float* b41 = (const float*)d_in[11];
  const float* w42 = (const float*)d_in[12];
  const float* b42 = (const float*)d_in[13];

  char* ws = (char*)d_ws;
  float*  P1       = (float*)(ws + oP1);
  float*  C2       = (float*)(ws + oC2);
  u64*    cands    = (u64*)(ws + oCand);
  u64*    selected = (u64*)(ws + oSel);
  u64*    keep     = (u64*)(ws + oKeep);
  u32*    misc     = (u32*)(ws + oMisc);
  float*  out      = (float*)d_out;

  k_conv1<<<T1RY * T1CX * BATCH, 256, 0, stream>>>(x, w1, b1, a1, P1, misc);
  k_conv2<<<C2TX * C2TY * BATCH, 256, 0, stream>>>(P1, w2, b2, a2, C2);
  k_conv3<<<C3TX * C3TY * BATCH, 256, 0, stream>>>(C2, w3, b3, a3, w41, b41, cands, misc);
  k_tail<<<1, 1024, 0, stream>>>(cands, misc, selected, keep);
  k_emit<<<(KSEL + 255) / 256, 256, 0, stream>>>(C2, w3, b3, a3, w42, b42, selected, keep, out);
}

// Round 15
// 617.613 us; speedup vs baseline: 1.6579x; 1.6579x over previous
//
#include <hip/hip_runtime.h>
#include <stdint.h>

using u32 = unsigned int;
using u64 = unsigned long long;

constexpr int BATCH = 4;
constexpr int H0 = 1080, W0 = 1920;     // input
constexpr int HP = 539,  WP = 959;      // after conv1(3x3 VALID)+pool2
constexpr int H2 = 537,  W2 = 957;      // after conv2
constexpr int H3 = 535,  W3 = 955;      // after conv3
constexpr int N3 = H3 * W3;             // 510925
constexpr int TOT3 = BATCH * N3;        // 2043700
constexpr int KSEL = 1024;
constexpr int SORTCAP = 4096;
constexpr float SCORE_THR_C = 0.6f;
constexpr float IOU_THR_C = 0.5f;
constexpr float IMG_OFF = 100000.0f;

// batched grids
constexpr int T1RY = 34, T1CX = 30;     // conv1: 16x32 pooled tile
constexpr int C2TY = 34, C2TX = 30;     // conv2: 16x32 tile (conv3-style)
constexpr int C3TY = 34, C3TX = 30;     // conv3: 16x32 tile

// ---------------- workspace layout (bytes) ----------------
constexpr size_t align256(size_t x) { return (x + 255) & ~(size_t)255; }
constexpr size_t oP1   = 0;
constexpr size_t sP1   = (size_t)BATCH * 10 * HP * WP * 4;     // 82.7 MB
constexpr size_t oC2   = align256(oP1 + sP1);
constexpr size_t sC2   = (size_t)BATCH * 16 * H2 * W2 * 4;     // 131.5 MB
constexpr size_t oCand = align256(oC2 + sC2);
constexpr size_t sCand = (size_t)TOT3 * 8;                     // 16.3 MB
constexpr size_t oSort = align256(oCand + sCand);
constexpr size_t oSel  = align256(oSort + (size_t)SORTCAP * 8);
constexpr size_t oBox  = align256(oSel + (size_t)KSEL * 8);
constexpr size_t oSup  = align256(oBox + (size_t)KSEL * 16);
constexpr size_t oKeep = align256(oSup + (size_t)KSEL * 16 * 8);
constexpr size_t oMisc = align256(oKeep + 16 * 8);
constexpr int    MISC_WORDS = 16 + 2048;   // [0]=cand_count [1]=sel_count [2]=bstar [3]=keff ; +16: hist[2048]
constexpr size_t WS_NEEDED = oMisc + (size_t)MISC_WORDS * 4;

__device__ __forceinline__ int keybin(u64 key) {
  u32 khi = (u32)(key >> 32);
  int d = (int)(khi - 0xC0800000u);   // scores in [0.5,1) land in [0, 0x800000)
  if (d < 0) d = 0;
  int bin = d >> 12;
  return bin > 2047 ? 2047 : bin;
}

// ---------------- conv1 + PReLU + 2x2 maxpool : LDS-tiled 16x32 pooled tile, 2 px/thread ----------------
// block 0 also zeros misc (replaces memset dispatch)
__global__ __launch_bounds__(256) void k_conv1(
    const float* __restrict__ x, const float* __restrict__ w1,
    const float* __restrict__ b1, const float* __restrict__ a1,
    float* __restrict__ P1, u32* __restrict__ misc) {
  __shared__ float sm[6834];
  int tid = threadIdx.x;
  int blk = blockIdx.x;
  if (blk == 0) {
    for (int i = tid; i < MISC_WORDS; i += 256) misc[i] = 0;
  }
  int btx = blk % T1CX; int r1 = blk / T1CX; int bty = r1 % T1RY; int b = r1 / T1RY;
  int r0 = 16 * bty; if (r0 > 523) r0 = 523;   // clamp; overlap recompute idempotent
  int c0 = 32 * btx; if (c0 > 927) c0 = 927;

  // stage x tile: rows 2r0..2r0+33, cols 2c0..2c0+65, 3 ci (stride 67)
  const float* xb = x + (size_t)b * 3 * H0 * W0;
  for (int i = tid; i < 6732; i += 256) {
    int ci = i / 2244; int rem = i - ci * 2244; int row = rem / 66; int col = rem - row * 66;
    sm[ci * 2278 + row * 67 + col] =
        xb[(size_t)ci * H0 * W0 + (size_t)(2 * r0 + row) * W0 + (2 * c0 + col)];
  }
  __syncthreads();

  int pr = tid >> 4, pc = tid & 15;     // pooled row 0..15, pooled-col-pair 0..15
  float acc[10][8];
  #pragma unroll
  for (int c = 0; c < 10; ++c) {
    float bb = b1[c];
    #pragma unroll
    for (int o = 0; o < 8; ++o) acc[c][o] = bb;
  }
  #pragma unroll 1
  for (int ci = 0; ci < 3; ++ci) {
    const float* sp = sm + ci * 2278 + (2 * pr) * 67 + 4 * pc;
    float in[4][6];
    #pragma unroll
    for (int iy = 0; iy < 4; ++iy)
      #pragma unroll
      for (int ix = 0; ix < 6; ++ix)
        in[iy][ix] = sp[iy * 67 + ix];
    #pragma unroll
    for (int c = 0; c < 10; ++c) {
      const float* wc = w1 + (c * 3 + ci) * 9;
      float w0v = wc[0], w1v = wc[1], w2v = wc[2], w3v = wc[3], w4v = wc[4],
            w5v = wc[5], w6v = wc[6], w7v = wc[7], w8v = wc[8];
      #pragma unroll
      for (int sr = 0; sr < 2; ++sr)
        #pragma unroll
        for (int sc = 0; sc < 4; ++sc) {
          float a = acc[c][sr * 4 + sc];
          a = fmaf(in[sr][sc],     w0v, a); a = fmaf(in[sr][sc+1],   w1v, a); a = fmaf(in[sr][sc+2],   w2v, a);
          a = fmaf(in[sr+1][sc],   w3v, a); a = fmaf(in[sr+1][sc+1], w4v, a); a = fmaf(in[sr+1][sc+2], w5v, a);
          a = fmaf(in[sr+2][sc],   w6v, a); a = fmaf(in[sr+2][sc+1], w7v, a); a = fmaf(in[sr+2][sc+2], w8v, a);
          acc[c][sr * 4 + sc] = a;
        }
    }
  }
  int gy = r0 + pr, gx = c0 + 2 * pc;
  size_t base = ((size_t)(b * 10) * HP + gy) * WP + gx;
  #pragma unroll
  for (int c = 0; c < 10; ++c) {
    float al = a1[c];
    float v[8];
    #pragma unroll
    for (int o = 0; o < 8; ++o) { float u = acc[c][o]; v[o] = u >= 0.0f ? u : al * u; }
    float m0 = fmaxf(fmaxf(v[0], v[1]), fmaxf(v[4], v[5]));
    float m1 = fmaxf(fmaxf(v[2], v[3]), fmaxf(v[6], v[7]));
    P1[base + (size_t)c * HP * WP]     = m0;
    P1[base + (size_t)c * HP * WP + 1] = m1;
  }
}

// ---------------- conv2 + PReLU : conv3-style 16x32 tile, 4 waves x 4 ch, 8 px/thread ----------------
// LDS: 10 ci x 18 rows x 35 stride = 6300 words (25.2 KB)
__global__ __launch_bounds__(256) void k_conv2(
    const float* __restrict__ P1, const float* __restrict__ w2,
    const float* __restrict__ b2, const float* __restrict__ a2,
    float* __restrict__ C2) {
  __shared__ float sm[6300];
  int tid = threadIdx.x;
  int blk = blockIdx.x;
  int tx = blk % C2TX; int r1 = blk / C2TX; int ty = r1 % C2TY; int b = r1 / C2TY;
  int r0 = 16 * ty; if (r0 > 521) r0 = 521;    // clamp; overlap stores idempotent
  int c0 = 32 * tx; if (c0 > 925) c0 = 925;

  // stage P1 tile: 10 ci x 18 rows x 34 cols (stride 35)
  const float* Pb = P1 + (size_t)b * 10 * HP * WP;
  for (int i = tid; i < 6120; i += 256) {
    int ci = i / 612; int rem = i - ci * 612; int row = rem / 34; int col = rem - row * 34;
    sm[ci * 630 + row * 35 + col] =
        Pb[(size_t)ci * HP * WP + (size_t)(r0 + row) * WP + (c0 + col)];
  }
  __syncthreads();

  int lane = tid & 63;
  int wv = __builtin_amdgcn_readfirstlane(tid >> 6);
  int c_lo = wv * 4;
  int rr = lane >> 3;      // row-pair 0..7
  int gg = lane & 7;       // col-group 0..7

  float acc[4][8];         // [c][d*4 + k]
  #pragma unroll
  for (int c = 0; c < 4; ++c) {
    float bb = b2[c_lo + c];
    #pragma unroll
    for (int o = 0; o < 8; ++o) acc[c][o] = bb;
  }
  #pragma unroll 1
  for (int ci = 0; ci < 10; ++ci) {
    const float* sp = sm + ci * 630 + (2 * rr) * 35 + 4 * gg;
    float in[4][6];
    #pragma unroll
    for (int dy = 0; dy < 4; ++dy)
      #pragma unroll
      for (int dx = 0; dx < 6; ++dx)
        in[dy][dx] = sp[dy * 35 + dx];
    #pragma unroll
    for (int c = 0; c < 4; ++c) {
      const float* wc = w2 + ((c_lo + c) * 10 + ci) * 9;
      float w0v = wc[0], w1v = wc[1], w2v = wc[2], w3v = wc[3], w4v = wc[4],
            w5v = wc[5], w6v = wc[6], w7v = wc[7], w8v = wc[8];
      #pragma unroll
      for (int d = 0; d < 2; ++d)
        #pragma unroll
        for (int k = 0; k < 4; ++k) {
          float a = acc[c][d * 4 + k];
          a = fmaf(in[d][k],   w0v, a); a = fmaf(in[d][k+1],   w1v, a); a = fmaf(in[d][k+2],   w2v, a);
          a = fmaf(in[d+1][k], w3v, a); a = fmaf(in[d+1][k+1], w4v, a); a = fmaf(in[d+1][k+2], w5v, a);
          a = fmaf(in[d+2][k], w6v, a); a = fmaf(in[d+2][k+1], w7v, a); a = fmaf(in[d+2][k+2], w8v, a);
          acc[c][d * 4 + k] = a;
        }
    }
  }
  #pragma unroll
  for (int c = 0; c < 4; ++c) {
    float al = a2[c_lo + c];
    #pragma unroll
    for (int d = 0; d < 2; ++d) {
      int gy = r0 + 2 * rr + d;
      size_t base = ((size_t)(b * 16 + c_lo + c) * H2 + gy) * W2 + (c0 + 4 * gg);
      #pragma unroll
      for (int k = 0; k < 4; ++k) {
        float v = acc[c][d * 4 + k];
        C2[base + k] = v >= 0.0f ? v : al * v;
      }
    }
  }
}

// ---------------- conv3 core (scalar 32-ch; used by k_emit only) ----------------
__device__ __forceinline__ void conv3_h(
    const float* __restrict__ C2, const float* __restrict__ w3,
    const float* __restrict__ b3, const float* __restrict__ a3,
    int b, int y, int x, float* h) {
  #pragma unroll
  for (int c = 0; c < 32; ++c) h[c] = b3[c];
  #pragma unroll 1
  for (int ci = 0; ci < 16; ++ci) {
    const float* p = C2 + ((size_t)(b * 16 + ci) * H2 + y) * W2 + x;
    float i0 = p[0],      i1 = p[1],      i2 = p[2];
    float i3 = p[W2],     i4 = p[W2+1],   i5 = p[W2+2];
    float i6 = p[2*W2],   i7 = p[2*W2+1], i8 = p[2*W2+2];
    const float* wp = w3 + ci * 9;
    #pragma unroll
    for (int c = 0; c < 32; ++c) {
      const float* wc = wp + c * 144;
      h[c] = fmaf(i0, wc[0], h[c]); h[c] = fmaf(i1, wc[1], h[c]);
      h[c] = fmaf(i2, wc[2], h[c]); h[c] = fmaf(i3, wc[3], h[c]);
      h[c] = fmaf(i4, wc[4], h[c]); h[c] = fmaf(i5, wc[5], h[c]);
      h[c] = fmaf(i6, wc[6], h[c]); h[c] = fmaf(i7, wc[7], h[c]);
      h[c] = fmaf(i8, wc[8], h[c]);
    }
  }
  #pragma unroll
  for (int c = 0; c < 32; ++c) h[c] = h[c] >= 0.0f ? h[c] : a3[c] * h[c];
}

// ---------------- conv3 + PReLU + head + filter + inline hist : tile 16x32, 4 waves x 8 ch, 8 px/thread ----------------
// R10-measured-fastest inner structure: rows (2rr, 2rr+1) with shared in[4][6] taps.
// LDS union: input tile 16ci x 18 x 35 = 10080 words (40.3 KB) ; h-half [32][256] = 8192 words
__global__ __launch_bounds__(256) void k_conv3(
    const float* __restrict__ C2, const float* __restrict__ w3,
    const float* __restrict__ b3, const float* __restrict__ a3,
    const float* __restrict__ w41, const float* __restrict__ b41,
    u64* __restrict__ cands, u32* __restrict__ misc) {
  __shared__ __align__(16) float sm[10080];
  int tid = threadIdx.x;
  int blk = blockIdx.x;
  int tx = blk % C3TX; int r1 = blk / C3TX; int ty = r1 % C3TY; int b = r1 / C3TY;
  int ymin = 16 * ty, xmin = 32 * tx;
  int r0 = ymin > 519 ? 519 : ymin;
  int c0 = xmin > 923 ? 923 : xmin;

  // phase A: stage 16ci x 18 x 34 input tile (row stride 35)
  const float* Cb = C2 + (size_t)b * 16 * H2 * W2;
  for (int i = tid; i < 9792; i += 256) {
    int ci = i / 612; int rem = i - ci * 612; int row = rem / 34; int col = rem - row * 34;
    sm[ci * 630 + row * 35 + col] =
        Cb[(size_t)ci * H2 * W2 + (size_t)(r0 + row) * W2 + (c0 + col)];
  }
  __syncthreads();

  // phase B: conv + PReLU. wave wv: channels 8wv..8wv+7; thread: rows 2rr..2rr+1, cols 4gg..4gg+3
  int lane = tid & 63;
  int wv = __builtin_amdgcn_readfirstlane(tid >> 6);
  int c_lo = wv * 8;
  int rr = lane >> 3;      // row-pair 0..7
  int gg = lane & 7;       // col-group 0..7

  float acc[8][8];         // [c][drow*4 + k]
  #pragma unroll
  for (int c = 0; c < 8; ++c) {
    float bb = b3[c_lo + c];
    #pragma unroll
    for (int o = 0; o < 8; ++o) acc[c][o] = bb;
  }
  #pragma unroll 1
  for (int ci = 0; ci < 16; ++ci) {
    const float* sp = sm + ci * 630 + (2 * rr) * 35 + 4 * gg;
    float in[4][6];
    #pragma unroll
    for (int dy = 0; dy < 4; ++dy)
      #pragma unroll
      for (int dx = 0; dx < 6; ++dx)
        in[dy][dx] = sp[dy * 35 + dx];
    #pragma unroll
    for (int c = 0; c < 8; ++c) {
      const float* wc = w3 + ((c_lo + c) * 16 + ci) * 9;
      float w0v = wc[0], w1v = wc[1], w2v = wc[2], w3v = wc[3], w4v = wc[4],
            w5v = wc[5], w6v = wc[6], w7v = wc[7], w8v = wc[8];
      #pragma unroll
      for (int d = 0; d < 2; ++d)
        #pragma unroll
        for (int k = 0; k < 4; ++k) {
          float a = acc[c][d * 4 + k];
          a = fmaf(in[d][k],   w0v, a); a = fmaf(in[d][k+1],   w1v, a); a = fmaf(in[d][k+2],   w2v, a);
          a = fmaf(in[d+1][k], w3v, a); a = fmaf(in[d+1][k+1], w4v, a); a = fmaf(in[d+1][k+2], w5v, a);
          a = fmaf(in[d+2][k], w6v, a); a = fmaf(in[d+2][k+1], w7v, a); a = fmaf(in[d+2][k+2], w8v, a);
          acc[c][d * 4 + k] = a;
        }
    }
  }
  #pragma unroll
  for (int c = 0; c < 8; ++c) {
    float al = a3[c_lo + c];
    #pragma unroll
    for (int o = 0; o < 8; ++o) {
      float v = acc[c][o];
      acc[c][o] = v >= 0.0f ? v : al * v;
    }
  }
  __syncthreads();   // input tile dead

  // phases C1/D1 then C2/D2: h-exchange + head, one 8-row half at a time (h[32][256] = 32 KB)
  #pragma unroll
  for (int halfp = 0; halfp < 2; ++halfp) {
    // C: threads owning this half's rows write their h values
    if ((rr >> 2) == halfp) {
      #pragma unroll
      for (int c = 0; c < 8; ++c)
        #pragma unroll
        for (int d = 0; d < 2; ++d) {
          int row = 2 * rr + d - 8 * halfp;    // 0..7 within half
          int word = (c_lo + c) * 256 + row * 32 + 4 * gg;
          *(float4*)&sm[word] = make_float4(acc[c][d*4+0], acc[c][d*4+1], acc[c][d*4+2], acc[c][d*4+3]);
        }
    }
    __syncthreads();
    // D: head per pixel (exact sequential c=0..31 sum), filter + push + inline hist
    {
      int p = tid;
      float l0 = b41[0], l1 = b41[1];
      #pragma unroll
      for (int c = 0; c < 32; ++c) {
        float hv = sm[c * 256 + p];
        l0 = fmaf(hv, w41[c],      l0);
        l1 = fmaf(hv, w41[32 + c], l1);
      }
      float prob = 1.0f / (1.0f + expf(l0 - l1));   // softmax[:,1] == sigmoid(l1-l0)
      int gy = r0 + 8 * halfp + (p >> 5);
      int gx = c0 + (p & 31);
      if (prob >= SCORE_THR_C && gy >= ymin && gx >= xmin) {
        u32 idx = (u32)(b * N3 + gy * W3 + gx);
        u64 key = ((u64)(~__float_as_uint(prob)) << 32) | idx;
        atomicAdd(&misc[16 + keybin(key)], 1u);     // inline histogram
        u32 pos = atomicAdd(&misc[0], 1u);
        cands[pos] = key;
      }
    }
    __syncthreads();
  }
}

// ---------------- top-k: compact with fused scan (each block derives bstar locally) ----------------
__global__ __launch_bounds__(256) void k_compact(const u64* __restrict__ cands,
                                                u32* __restrict__ misc,
                                                u64* __restrict__ sortbuf) {
  __shared__ u32 lh[2048];
  __shared__ u32 part[256];
  __shared__ u32 sb;
  int tid = threadIdx.x;
  const u32* hist = misc + 16;
  for (int t = tid; t < 2048; t += 256) lh[t] = hist[t];
  __syncthreads();
  u32 s = 0;
  #pragma unroll
  for (int k = 0; k < 8; ++k) s += lh[tid * 8 + k];
  part[tid] = s;
  __syncthreads();
  if (tid == 0) {
    u32 total = misc[0]; if (total > (u32)TOT3) total = TOT3;
    u32 keff = total < (u32)KSEL ? total : (u32)KSEL;
    u32 run = 0; int chunk = 255;
    for (int t = 0; t < 256; ++t) {
      if (run + part[t] >= keff) { chunk = t; break; }
      run += part[t];
    }
    int bstar = 2047;
    for (int b = chunk * 8; b < chunk * 8 + 8; ++b) {
      u32 hv = lh[b];
      if (run + hv >= keff) { bstar = b; break; }
      run += hv;
    }
    sb = (u32)bstar;
    if (blockIdx.x == 0) { misc[2] = (u32)bstar; misc[3] = keff; }   // for k_nms
  }
  __syncthreads();
  int bstar = (int)sb;
  u32 n = misc[0]; if (n > (u32)TOT3) n = TOT3;
  u32 stride = gridDim.x * 256;
  for (u32 i = blockIdx.x * 256 + tid; i < n; i += stride) {
    u64 key = cands[i];
    if (keybin(key) <= bstar) {
      u32 pos = atomicAdd(&misc[1], 1u);
      if (pos < (u32)SORTCAP) sortbuf[pos] = key;
    }
  }
}

// bitonic sort (adaptive pow2 size >= nsel) in LDS; emit sorted top-1024 keys + NMS boxes
__global__ __launch_bounds__(1024) void k_sort(const u64* __restrict__ sortbuf,
                                               const u32* __restrict__ misc,
                                               u64* __restrict__ selected,
                                               float4* __restrict__ boxarr) {
  __shared__ u64 s[SORTCAP];
  int tid = threadIdx.x;
  u32 nsel = misc[1]; if (nsel > (u32)SORTCAP) nsel = SORTCAP;
  unsigned m = KSEL;
  while (m < nsel) m <<= 1;              // uniform across block
  for (int t = tid; t < (int)m; t += 1024) s[t] = (t < (int)nsel) ? sortbuf[t] : ~0ULL;
  for (unsigned k = 2; k <= m; k <<= 1) {
    for (unsigned j = k >> 1; j > 0; j >>= 1) {
      __syncthreads();
      for (int t = tid; t < (int)m; t += 1024) {
        int ixj = t ^ (int)j;
        if (ixj > t) {
          u64 a = s[t], b = s[ixj];
          bool up = ((t & (int)k) == 0);
          if ((a > b) == up) { s[t] = b; s[ixj] = a; }
        }
      }
    }
  }
  __syncthreads();
  if (tid < KSEL) {
    u64 key = s[tid];
    selected[tid] = key;
    u32 idx = (u32)key;
    u32 b = idx / (u32)N3;
    u32 rem = idx - b * (u32)N3;
    u32 y = rem / (u32)W3;
    u32 x = rem - y * (u32)W3;
    float off = (float)b * IMG_OFF;
    float x1 = (float)(2 * (int)x + 1) + off;
    float y1 = (float)(2 * (int)y + 1) + off;
    boxarr[tid] = make_float4(x1, y1, x1 + 11.0f, y1 + 11.0f);
  }
}

// ---------------- NMS: suppression bitmask matrix ----------------
__global__ __launch_bounds__(256) void k_sup(const float4* __restrict__ boxarr,
                                             u64* __restrict__ sup) {
  __shared__ float4 lbox[KSEL];
  int tid = threadIdx.x;
  for (int t = tid; t < KSEL; t += 256) lbox[t] = boxarr[t];
  __syncthreads();
  int i = blockIdx.x * 16 + (tid >> 4);
  int w = tid & 15;
  float4 bi = lbox[i];
  float ai = (bi.z - bi.x) * (bi.w - bi.y);
  u64 m = 0;
  #pragma unroll 4
  for (int jj = 0; jj < 64; ++jj) {
    int j = (w << 6) + jj;
    float4 bj = lbox[j];
    float xx1 = fmaxf(bi.x, bj.x), yy1 = fmaxf(bi.y, bj.y);
    float xx2 = fminf(bi.z, bj.z), yy2 = fminf(bi.w, bj.w);
    float inter = fmaxf(xx2 - xx1, 0.0f) * fmaxf(yy2 - yy1, 0.0f);
    float aj = (bj.z - bj.x) * (bj.w - bj.y);
    float iou = inter / (ai + aj - inter);
    if (iou > IOU_THR_C && j > i) m |= (1ULL << jj);
  }
  sup[(size_t)i * 16 + w] = m;
}

// block-parallel greedy NMS: 16 column-blocks of 64, wave-uniform intra-block bit loop.
// Identical accept order/semantics to the sequential greedy (sup rows carry only j>i bits).
__global__ __launch_bounds__(256) void k_nms(const u64* __restrict__ sup,
                                             const u32* __restrict__ misc,
                                             u64* __restrict__ keep) {
  __shared__ u64 lsup[512 * 16];    // 64 KB (rows of one chunk)
  __shared__ u64 rem[16];           // accumulated suppression from accepted boxes
  __shared__ u64 keepres[16];
  int tid = threadIdx.x;
  int lane = tid & 63;
  int total = (int)misc[3];
  if (tid < 16) {
    rem[tid] = 0;
    int nb = total - tid * 64;
    keepres[tid] = nb >= 64 ? ~0ULL : (nb <= 0 ? 0ULL : ((1ULL << nb) - 1ULL));
  }
  for (int chunk = 0; chunk < 2; ++chunk) {
    for (int t = tid; t < 512 * 16; t += 256) lsup[t] = sup[(size_t)chunk * 512 * 16 + t];
    __syncthreads();
    for (int jb = 0; jb < 8; ++jb) {
      int j = chunk * 8 + jb;          // global block index 0..15
      if (tid < 64) {
        u64 intra = lsup[(jb * 64 + lane) * 16 + j];
        u64 kw = keepres[j] & ~rem[j];
        #pragma unroll 8
        for (int bbit = 0; bbit < 64; ++bbit) {
          u64 row = __shfl(intra, bbit);
          if ((kw >> bbit) & 1ULL) kw &= ~row;
        }
        if (lane == 0) keepres[j] = kw;
      }
      __syncthreads();
      if (tid < 16) {
        u64 kw = keepres[j];
        u64 r = rem[tid];
        int base = jb * 64;
        while (kw) {
          int bbit = __ffsll(kw) - 1;
          kw &= kw - 1;
          r |= lsup[(base + bbit) * 16 + tid];
        }
        rem[tid] = r;
      }
      __syncthreads();
    }
  }
  if (tid < 16) keep[tid] = keepres[tid];
}

// ---------------- final emit: recompute pred head for kept rows ----------------
__global__ __launch_bounds__(256) void k_emit(
    const float* __restrict__ C2, const float* __restrict__ w3,
    const float* __restrict__ b3, const float* __restrict__ a3,
    const float* __restrict__ w42, const float* __restrict__ b42,
    const u64* __restrict__ selected, const u64* __restrict__ keep,
    float* __restrict__ out) {
  int r = blockIdx.x * 256 + threadIdx.x;
  if (r >= KSEL) return;
  bool kb = (keep[r >> 6] >> (r & 63)) & 1ULL;
  if (!kb) {
    out[r*5+0] = 0.0f; out[r*5+1] = 0.0f; out[r*5+2] = 0.0f;
    out[r*5+3] = 0.0f; out[r*5+4] = 0.0f;
    return;
  }
  u64 key = selected[r];
  float score = __uint_as_float(~(u32)(key >> 32));
  u32 idx = (u32)key;
  int b = (int)(idx / (u32)N3);
  int rem = (int)(idx - (u32)b * (u32)N3);
  int y = rem / W3;
  int x = rem - y * W3;
  float h[32];
  conv3_h(C2, w3, b3, a3, b, y, x, h);
  float p0 = b42[0], p1 = b42[1], p2 = b42[2], p3 = b42[3];
  #pragma unroll
  for (int c = 0; c < 32; ++c) {
    p0 = fmaf(h[c], w42[c],      p0);
    p1 = fmaf(h[c], w42[32 + c], p1);
    p2 = fmaf(h[c], w42[64 + c], p2);
    p3 = fmaf(h[c], w42[96 + c], p3);
  }
  float x1 = (float)(2 * x + 1), y1f = (float)(2 * y + 1);
  float x2 = (float)(2 * x + 12), y2f = (float)(2 * y + 12);
  float bw = x2 - x1, bh = y2f - y1f;
  float rx1 = fmaf(p0, bw, x1), ry1 = fmaf(p1, bh, y1f);
  float rx2 = fmaf(p2, bw, x2), ry2 = fmaf(p3, bh, y2f);
  float rw = rx2 - rx1, rh = ry2 - ry1;
  float l = fmaxf(rw, rh);
  float ox1 = rx1 + 0.5f * rw - 0.5f * l;
  float oy1 = ry1 + 0.5f * rh - 0.5f * l;
  out[r*5+0] = ox1; out[r*5+1] = oy1;
  out[r*5+2] = ox1 + l; out[r*5+3] = oy1 + l;
  out[r*5+4] = score;
}

extern "C" void kernel_launch(void* const* d_in, const int* in_sizes, int n_in,
                              void* d_out, int out_size, void* d_ws, size_t ws_size,
                              hipStream_t stream) {
  if (ws_size < WS_NEEDED) return;
  const float* x   = (const float*)d_in[0];
  const float* w1  = (const float*)d_in[1];
  const float* b1  = (const float*)d_in[2];
  const float* a1  = (const float*)d_in[3];
  const float* w2  = (const float*)d_in[4];
  const float* b2  = (const float*)d_in[5];
  const float* a2  = (const float*)d_in[6];
  const float* w3  = (const float*)d_in[7];
  const float* b3  = (const float*)d_in[8];
  const float* a3  = (const float*)d_in[9];
  const float* w41 = (const float*)d_in[10];
  const float* b41 = (const float*)d_in[11];
  const float* w42 = (const float*)d_in[12];
  const float* b42 = (const float*)d_in[13];

  char* ws = (char*)d_ws;
  float*  P1       = (float*)(ws + oP1);
  float*  C2       = (float*)(ws + oC2);
  u64*    cands    = (u64*)(ws + oCand);
  u64*    sortbuf  = (u64*)(ws + oSort);
  u64*    selected = (u64*)(ws + oSel);
  float4* boxarr   = (float4*)(ws + oBox);
  u64*    sup      = (u64*)(ws + oSup);
  u64*    keep     = (u64*)(ws + oKeep);
  u32*    misc     = (u32*)(ws + oMisc);
  float*  out      = (float*)d_out;

  k_conv1<<<T1RY * T1CX * BATCH, 256, 0, stream>>>(x, w1, b1, a1, P1, misc);
  k_conv2<<<C2TX * C2TY * BATCH, 256, 0, stream>>>(P1, w2, b2, a2, C2);
  k_conv3<<<C3TX * C3TY * BATCH, 256, 0, stream>>>(C2, w3, b3, a3, w41, b41, cands, misc);
  k_compact<<<512, 256, 0, stream>>>(cands, misc, sortbuf);
  k_sort<<<1, 1024, 0, stream>>>(sortbuf, misc, selected, boxarr);
  k_sup<<<64, 256, 0, stream>>>(boxarr, sup);
  k_nms<<<1, 256, 0, stream>>>(sup, misc, keep);
  k_emit<<<(KSEL + 255) / 256, 256, 0, stream>>>(C2, w3, b3, a3, w42, b42, selected, keep, out);
}

// Round 16
// 570.885 us; speedup vs baseline: 1.7935x; 1.0819x over previous
//
#include <hip/hip_runtime.h>
#include <stdint.h>

using u32 = unsigned int;
using u64 = unsigned long long;

constexpr int BATCH = 4;
constexpr int H0 = 1080, W0 = 1920;     // input
constexpr int HP = 539,  WP = 959;      // after conv1(3x3 VALID)+pool2
constexpr int H2 = 537,  W2 = 957;      // after conv2
constexpr int H3 = 535,  W3 = 955;      // after conv3
constexpr int N3 = H3 * W3;             // 510925
constexpr int TOT3 = BATCH * N3;        // 2043700
constexpr int KSEL = 1024;
constexpr int SORTCAP = 4096;
constexpr float SCORE_THR_C = 0.6f;
constexpr float IOU_THR_C = 0.5f;
constexpr float IMG_OFF = 100000.0f;

// batched grids
constexpr int C2TY = 34, C2TX = 30;     // conv12: 16x32 conv2-output tile
constexpr int C3TY = 34, C3TX = 30;     // conv3: 16x32 tile

// ---------------- workspace layout (bytes) ----------------
constexpr size_t align256(size_t x) { return (x + 255) & ~(size_t)255; }
constexpr size_t oC2   = 0;
constexpr size_t sC2   = (size_t)BATCH * 16 * H2 * W2 * 4;     // 131.5 MB
constexpr size_t oCand = align256(oC2 + sC2);
constexpr size_t sCand = (size_t)TOT3 * 8;                     // 16.3 MB
constexpr size_t oSort = align256(oCand + sCand);
constexpr size_t oSel  = align256(oSort + (size_t)SORTCAP * 8);
constexpr size_t oBox  = align256(oSel + (size_t)KSEL * 8);
constexpr size_t oSup  = align256(oBox + (size_t)KSEL * 16);
constexpr size_t oKeep = align256(oSup + (size_t)KSEL * 16 * 8);
constexpr size_t oMisc = align256(oKeep + 16 * 8);
constexpr int    MISC_WORDS = 16 + 2048;   // [0]=cand_count [1]=sel_count [2]=bstar [3]=keff ; +16: hist[2048]
constexpr size_t WS_NEEDED = oMisc + (size_t)MISC_WORDS * 4;

__device__ __forceinline__ int keybin(u64 key) {
  u32 khi = (u32)(key >> 32);
  int d = (int)(khi - 0xC0800000u);   // scores in [0.5,1) land in [0, 0x800000)
  if (d < 0) d = 0;
  int bin = d >> 12;
  return bin > 2047 ? 2047 : bin;
}

// ---------------- fused conv1+pool+conv2 : one 16x32 conv2-output tile per block ----------------
// Phase A: stage x tile 3ci x 38 x 70 (stride 71, 32.4 KB).
// Phase B: conv1+PReLU+pool to REGISTERS (1 pooled px x 10 ch per task, 612 px);
//          barrier; overwrite dead x region with p1t[10][18][35] (25.2 KB < 32.4 KB).
// Phase C: conv2 (R15 k_conv2 body, byte-identical FMA order) reading p1t.
__global__ __launch_bounds__(256) void k_conv12(
    const float* __restrict__ x, const float* __restrict__ w1,
    const float* __restrict__ b1, const float* __restrict__ a1,
    const float* __restrict__ w2, const float* __restrict__ b2,
    const float* __restrict__ a2,
    float* __restrict__ C2, u32* __restrict__ misc) {
  __shared__ float sm[8094];     // max(x tile 8094, p1t 6300)
  int tid = threadIdx.x;
  int blk = blockIdx.x;
  if (blk == 0) {
    for (int i = tid; i < MISC_WORDS; i += 256) misc[i] = 0;
  }
  int tx = blk % C2TX; int r1 = blk / C2TX; int ty = r1 % C2TY; int b = r1 / C2TY;
  int r0 = 16 * ty; if (r0 > 521) r0 = 521;    // clamp; overlap recompute idempotent
  int c0 = 32 * tx; if (c0 > 925) c0 = 925;

  // phase A: stage x rows 2r0..2r0+37, cols 2c0..2c0+69, 3 ci
  const float* xb = x + (size_t)b * 3 * H0 * W0;
  for (int i = tid; i < 7980; i += 256) {
    int ci = i / 2660; int rem = i - ci * 2660; int row = rem / 70; int col = rem - row * 70;
    sm[ci * 2698 + row * 71 + col] =
        xb[(size_t)ci * H0 * W0 + (size_t)(2 * r0 + row) * W0 + (2 * c0 + col)];
  }
  __syncthreads();

  // phase B: conv1 + PReLU + pool for the 18x34 pooled halo, into registers
  float pool[3][10];
  #pragma unroll
  for (int it = 0; it < 3; ++it) {
    int p = tid + it * 256;
    if (p < 612) {
      int py = p / 34, pxc = p - py * 34;
      float accv[10][4];
      #pragma unroll
      for (int c = 0; c < 10; ++c) {
        float bb = b1[c];
        accv[c][0] = bb; accv[c][1] = bb; accv[c][2] = bb; accv[c][3] = bb;
      }
      #pragma unroll 1
      for (int ci = 0; ci < 3; ++ci) {
        const float* sp = sm + ci * 2698 + (2 * py) * 71 + 2 * pxc;
        float in[4][4];
        #pragma unroll
        for (int dy = 0; dy < 4; ++dy)
          #pragma unroll
          for (int dx = 0; dx < 4; ++dx)
            in[dy][dx] = sp[dy * 71 + dx];
        #pragma unroll
        for (int c = 0; c < 10; ++c) {
          const float* wc = w1 + (c * 3 + ci) * 9;
          float w0v = wc[0], w1v = wc[1], w2v = wc[2], w3v = wc[3], w4v = wc[4],
                w5v = wc[5], w6v = wc[6], w7v = wc[7], w8v = wc[8];
          #pragma unroll
          for (int sy = 0; sy < 2; ++sy)
            #pragma unroll
            for (int sx = 0; sx < 2; ++sx) {
              float a = accv[c][sy * 2 + sx];
              a = fmaf(in[sy][sx],     w0v, a); a = fmaf(in[sy][sx+1],   w1v, a); a = fmaf(in[sy][sx+2],   w2v, a);
              a = fmaf(in[sy+1][sx],   w3v, a); a = fmaf(in[sy+1][sx+1], w4v, a); a = fmaf(in[sy+1][sx+2], w5v, a);
              a = fmaf(in[sy+2][sx],   w6v, a); a = fmaf(in[sy+2][sx+1], w7v, a); a = fmaf(in[sy+2][sx+2], w8v, a);
              accv[c][sy * 2 + sx] = a;
            }
        }
      }
      #pragma unroll
      for (int c = 0; c < 10; ++c) {
        float al = a1[c];
        float v0 = accv[c][0] >= 0.0f ? accv[c][0] : al * accv[c][0];
        float v1 = accv[c][1] >= 0.0f ? accv[c][1] : al * accv[c][1];
        float v2 = accv[c][2] >= 0.0f ? accv[c][2] : al * accv[c][2];
        float v3 = accv[c][3] >= 0.0f ? accv[c][3] : al * accv[c][3];
        pool[it][c] = fmaxf(fmaxf(v0, v1), fmaxf(v2, v3));
      }
    }
  }
  __syncthreads();   // all x-tile reads complete

  // write p1t over the dead x region: p1t[c][py][pxc], stride 35
  #pragma unroll
  for (int it = 0; it < 3; ++it) {
    int p = tid + it * 256;
    if (p < 612) {
      int py = p / 34, pxc = p - py * 34;
      #pragma unroll
      for (int c = 0; c < 10; ++c)
        sm[c * 630 + py * 35 + pxc] = pool[it][c];
    }
  }
  __syncthreads();

  // phase C: conv2 + PReLU (R15 body)
  int lane = tid & 63;
  int wv = __builtin_amdgcn_readfirstlane(tid >> 6);
  int c_lo = wv * 4;
  int rr = lane >> 3;      // row-pair 0..7
  int gg = lane & 7;       // col-group 0..7

  float acc[4][8];         // [c][d*4 + k]
  #pragma unroll
  for (int c = 0; c < 4; ++c) {
    float bb = b2[c_lo + c];
    #pragma unroll
    for (int o = 0; o < 8; ++o) acc[c][o] = bb;
  }
  #pragma unroll 1
  for (int ci = 0; ci < 10; ++ci) {
    const float* sp = sm + ci * 630 + (2 * rr) * 35 + 4 * gg;
    float in[4][6];
    #pragma unroll
    for (int dy = 0; dy < 4; ++dy)
      #pragma unroll
      for (int dx = 0; dx < 6; ++dx)
        in[dy][dx] = sp[dy * 35 + dx];
    #pragma unroll
    for (int c = 0; c < 4; ++c) {
      const float* wc = w2 + ((c_lo + c) * 10 + ci) * 9;
      float w0v = wc[0], w1v = wc[1], w2v = wc[2], w3v = wc[3], w4v = wc[4],
            w5v = wc[5], w6v = wc[6], w7v = wc[7], w8v = wc[8];
      #pragma unroll
      for (int d = 0; d < 2; ++d)
        #pragma unroll
        for (int k = 0; k < 4; ++k) {
          float a = acc[c][d * 4 + k];
          a = fmaf(in[d][k],   w0v, a); a = fmaf(in[d][k+1],   w1v, a); a = fmaf(in[d][k+2],   w2v, a);
          a = fmaf(in[d+1][k], w3v, a); a = fmaf(in[d+1][k+1], w4v, a); a = fmaf(in[d+1][k+2], w5v, a);
          a = fmaf(in[d+2][k], w6v, a); a = fmaf(in[d+2][k+1], w7v, a); a = fmaf(in[d+2][k+2], w8v, a);
          acc[c][d * 4 + k] = a;
        }
    }
  }
  #pragma unroll
  for (int c = 0; c < 4; ++c) {
    float al = a2[c_lo + c];
    #pragma unroll
    for (int d = 0; d < 2; ++d) {
      int gy = r0 + 2 * rr + d;
      size_t base = ((size_t)(b * 16 + c_lo + c) * H2 + gy) * W2 + (c0 + 4 * gg);
      #pragma unroll
      for (int k = 0; k < 4; ++k) {
        float v = acc[c][d * 4 + k];
        C2[base + k] = v >= 0.0f ? v : al * v;
      }
    }
  }
}

// ---------------- conv3 core (scalar 32-ch; used by k_emit only) ----------------
__device__ __forceinline__ void conv3_h(
    const float* __restrict__ C2, const float* __restrict__ w3,
    const float* __restrict__ b3, const float* __restrict__ a3,
    int b, int y, int x, float* h) {
  #pragma unroll
  for (int c = 0; c < 32; ++c) h[c] = b3[c];
  #pragma unroll 1
  for (int ci = 0; ci < 16; ++ci) {
    const float* p = C2 + ((size_t)(b * 16 + ci) * H2 + y) * W2 + x;
    float i0 = p[0],      i1 = p[1],      i2 = p[2];
    float i3 = p[W2],     i4 = p[W2+1],   i5 = p[W2+2];
    float i6 = p[2*W2],   i7 = p[2*W2+1], i8 = p[2*W2+2];
    const float* wp = w3 + ci * 9;
    #pragma unroll
    for (int c = 0; c < 32; ++c) {
      const float* wc = wp + c * 144;
      h[c] = fmaf(i0, wc[0], h[c]); h[c] = fmaf(i1, wc[1], h[c]);
      h[c] = fmaf(i2, wc[2], h[c]); h[c] = fmaf(i3, wc[3], h[c]);
      h[c] = fmaf(i4, wc[4], h[c]); h[c] = fmaf(i5, wc[5], h[c]);
      h[c] = fmaf(i6, wc[6], h[c]); h[c] = fmaf(i7, wc[7], h[c]);
      h[c] = fmaf(i8, wc[8], h[c]);
    }
  }
  #pragma unroll
  for (int c = 0; c < 32; ++c) h[c] = h[c] >= 0.0f ? h[c] : a3[c] * h[c];
}

// ---------------- conv3 + PReLU + head + filter + inline hist : tile 16x32, 4 waves x 8 ch, 8 px/thread ----------------
__global__ __launch_bounds__(256) void k_conv3(
    const float* __restrict__ C2, const float* __restrict__ w3,
    const float* __restrict__ b3, const float* __restrict__ a3,
    const float* __restrict__ w41, const float* __restrict__ b41,
    u64* __restrict__ cands, u32* __restrict__ misc) {
  __shared__ __align__(16) float sm[10080];
  int tid = threadIdx.x;
  int blk = blockIdx.x;
  int tx = blk % C3TX; int r1 = blk / C3TX; int ty = r1 % C3TY; int b = r1 / C3TY;
  int ymin = 16 * ty, xmin = 32 * tx;
  int r0 = ymin > 519 ? 519 : ymin;
  int c0 = xmin > 923 ? 923 : xmin;

  const float* Cb = C2 + (size_t)b * 16 * H2 * W2;
  for (int i = tid; i < 9792; i += 256) {
    int ci = i / 612; int rem = i - ci * 612; int row = rem / 34; int col = rem - row * 34;
    sm[ci * 630 + row * 35 + col] =
        Cb[(size_t)ci * H2 * W2 + (size_t)(r0 + row) * W2 + (c0 + col)];
  }
  __syncthreads();

  int lane = tid & 63;
  int wv = __builtin_amdgcn_readfirstlane(tid >> 6);
  int c_lo = wv * 8;
  int rr = lane >> 3;
  int gg = lane & 7;

  float acc[8][8];
  #pragma unroll
  for (int c = 0; c < 8; ++c) {
    float bb = b3[c_lo + c];
    #pragma unroll
    for (int o = 0; o < 8; ++o) acc[c][o] = bb;
  }
  #pragma unroll 1
  for (int ci = 0; ci < 16; ++ci) {
    const float* sp = sm + ci * 630 + (2 * rr) * 35 + 4 * gg;
    float in[4][6];
    #pragma unroll
    for (int dy = 0; dy < 4; ++dy)
      #pragma unroll
      for (int dx = 0; dx < 6; ++dx)
        in[dy][dx] = sp[dy * 35 + dx];
    #pragma unroll
    for (int c = 0; c < 8; ++c) {
      const float* wc = w3 + ((c_lo + c) * 16 + ci) * 9;
      float w0v = wc[0], w1v = wc[1], w2v = wc[2], w3v = wc[3], w4v = wc[4],
            w5v = wc[5], w6v = wc[6], w7v = wc[7], w8v = wc[8];
      #pragma unroll
      for (int d = 0; d < 2; ++d)
        #pragma unroll
        for (int k = 0; k < 4; ++k) {
          float a = acc[c][d * 4 + k];
          a = fmaf(in[d][k],   w0v, a); a = fmaf(in[d][k+1],   w1v, a); a = fmaf(in[d][k+2],   w2v, a);
          a = fmaf(in[d+1][k], w3v, a); a = fmaf(in[d+1][k+1], w4v, a); a = fmaf(in[d+1][k+2], w5v, a);
          a = fmaf(in[d+2][k], w6v, a); a = fmaf(in[d+2][k+1], w7v, a); a = fmaf(in[d+2][k+2], w8v, a);
          acc[c][d * 4 + k] = a;
        }
    }
  }
  #pragma unroll
  for (int c = 0; c < 8; ++c) {
    float al = a3[c_lo + c];
    #pragma unroll
    for (int o = 0; o < 8; ++o) {
      float v = acc[c][o];
      acc[c][o] = v >= 0.0f ? v : al * v;
    }
  }
  __syncthreads();

  #pragma unroll
  for (int halfp = 0; halfp < 2; ++halfp) {
    if ((rr >> 2) == halfp) {
      #pragma unroll
      for (int c = 0; c < 8; ++c)
        #pragma unroll
        for (int d = 0; d < 2; ++d) {
          int row = 2 * rr + d - 8 * halfp;
          int word = (c_lo + c) * 256 + row * 32 + 4 * gg;
          *(float4*)&sm[word] = make_float4(acc[c][d*4+0], acc[c][d*4+1], acc[c][d*4+2], acc[c][d*4+3]);
        }
    }
    __syncthreads();
    {
      int p = tid;
      float l0 = b41[0], l1 = b41[1];
      #pragma unroll
      for (int c = 0; c < 32; ++c) {
        float hv = sm[c * 256 + p];
        l0 = fmaf(hv, w41[c],      l0);
        l1 = fmaf(hv, w41[32 + c], l1);
      }
      float prob = 1.0f / (1.0f + expf(l0 - l1));
      int gy = r0 + 8 * halfp + (p >> 5);
      int gx = c0 + (p & 31);
      if (prob >= SCORE_THR_C && gy >= ymin && gx >= xmin) {
        u32 idx = (u32)(b * N3 + gy * W3 + gx);
        u64 key = ((u64)(~__float_as_uint(prob)) << 32) | idx;
        atomicAdd(&misc[16 + keybin(key)], 1u);
        u32 pos = atomicAdd(&misc[0], 1u);
        cands[pos] = key;
      }
    }
    __syncthreads();
  }
}

// ---------------- top-k: compact with fused scan (each block derives bstar locally) ----------------
__global__ __launch_bounds__(256) void k_compact(const u64* __restrict__ cands,
                                                u32* __restrict__ misc,
                                                u64* __restrict__ sortbuf) {
  __shared__ u32 lh[2048];
  __shared__ u32 part[256];
  __shared__ u32 sb;
  int tid = threadIdx.x;
  const u32* hist = misc + 16;
  for (int t = tid; t < 2048; t += 256) lh[t] = hist[t];
  __syncthreads();
  u32 s = 0;
  #pragma unroll
  for (int k = 0; k < 8; ++k) s += lh[tid * 8 + k];
  part[tid] = s;
  __syncthreads();
  if (tid == 0) {
    u32 total = misc[0]; if (total > (u32)TOT3) total = TOT3;
    u32 keff = total < (u32)KSEL ? total : (u32)KSEL;
    u32 run = 0; int chunk = 255;
    for (int t = 0; t < 256; ++t) {
      if (run + part[t] >= keff) { chunk = t; break; }
      run += part[t];
    }
    int bstar = 2047;
    for (int b = chunk * 8; b < chunk * 8 + 8; ++b) {
      u32 hv = lh[b];
      if (run + hv >= keff) { bstar = b; break; }
      run += hv;
    }
    sb = (u32)bstar;
    if (blockIdx.x == 0) { misc[2] = (u32)bstar; misc[3] = keff; }   // for k_nms
  }
  __syncthreads();
  int bstar = (int)sb;
  u32 n = misc[0]; if (n > (u32)TOT3) n = TOT3;
  u32 stride = gridDim.x * 256;
  for (u32 i = blockIdx.x * 256 + tid; i < n; i += stride) {
    u64 key = cands[i];
    if (keybin(key) <= bstar) {
      u32 pos = atomicAdd(&misc[1], 1u);
      if (pos < (u32)SORTCAP) sortbuf[pos] = key;
    }
  }
}

// bitonic sort (adaptive pow2 size >= nsel) in LDS; emit sorted top-1024 keys + NMS boxes
__global__ __launch_bounds__(1024) void k_sort(const u64* __restrict__ sortbuf,
                                               const u32* __restrict__ misc,
                                               u64* __restrict__ selected,
                                               float4* __restrict__ boxarr) {
  __shared__ u64 s[SORTCAP];
  int tid = threadIdx.x;
  u32 nsel = misc[1]; if (nsel > (u32)SORTCAP) nsel = SORTCAP;
  unsigned m = KSEL;
  while (m < nsel) m <<= 1;              // uniform across block
  for (int t = tid; t < (int)m; t += 1024) s[t] = (t < (int)nsel) ? sortbuf[t] : ~0ULL;
  for (unsigned k = 2; k <= m; k <<= 1) {
    for (unsigned j = k >> 1; j > 0; j >>= 1) {
      __syncthreads();
      for (int t = tid; t < (int)m; t += 1024) {
        int ixj = t ^ (int)j;
        if (ixj > t) {
          u64 a = s[t], b = s[ixj];
          bool up = ((t & (int)k) == 0);
          if ((a > b) == up) { s[t] = b; s[ixj] = a; }
        }
      }
    }
  }
  __syncthreads();
  if (tid < KSEL) {
    u64 key = s[tid];
    selected[tid] = key;
    u32 idx = (u32)key;
    u32 b = idx / (u32)N3;
    u32 rem = idx - b * (u32)N3;
    u32 y = rem / (u32)W3;
    u32 x = rem - y * (u32)W3;
    float off = (float)b * IMG_OFF;
    float x1 = (float)(2 * (int)x + 1) + off;
    float y1 = (float)(2 * (int)y + 1) + off;
    boxarr[tid] = make_float4(x1, y1, x1 + 11.0f, y1 + 11.0f);
  }
}

// ---------------- NMS: suppression bitmask matrix ----------------
__global__ __launch_bounds__(256) void k_sup(const float4* __restrict__ boxarr,
                                             u64* __restrict__ sup) {
  __shared__ float4 lbox[KSEL];
  int tid = threadIdx.x;
  for (int t = tid; t < KSEL; t += 256) lbox[t] = boxarr[t];
  __syncthreads();
  int i = blockIdx.x * 16 + (tid >> 4);
  int w = tid & 15;
  float4 bi = lbox[i];
  float ai = (bi.z - bi.x) * (bi.w - bi.y);
  u64 m = 0;
  #pragma unroll 4
  for (int jj = 0; jj < 64; ++jj) {
    int j = (w << 6) + jj;
    float4 bj = lbox[j];
    float xx1 = fmaxf(bi.x, bj.x), yy1 = fmaxf(bi.y, bj.y);
    float xx2 = fminf(bi.z, bj.z), yy2 = fminf(bi.w, bj.w);
    float inter = fmaxf(xx2 - xx1, 0.0f) * fmaxf(yy2 - yy1, 0.0f);
    float aj = (bj.z - bj.x) * (bj.w - bj.y);
    float iou = inter / (ai + aj - inter);
    if (iou > IOU_THR_C && j > i) m |= (1ULL << jj);
  }
  sup[(size_t)i * 16 + w] = m;
}

// block-parallel greedy NMS: 16 column-blocks of 64, wave-uniform intra-block bit loop.
__global__ __launch_bounds__(256) void k_nms(const u64* __restrict__ sup,
                                             const u32* __restrict__ misc,
                                             u64* __restrict__ keep) {
  __shared__ u64 lsup[512 * 16];    // 64 KB (rows of one chunk)
  __shared__ u64 rem[16];           // accumulated suppression from accepted boxes
  __shared__ u64 keepres[16];
  int tid = threadIdx.x;
  int lane = tid & 63;
  int total = (int)misc[3];
  if (tid < 16) {
    rem[tid] = 0;
    int nb = total - tid * 64;
    keepres[tid] = nb >= 64 ? ~0ULL : (nb <= 0 ? 0ULL : ((1ULL << nb) - 1ULL));
  }
  for (int chunk = 0; chunk < 2; ++chunk) {
    for (int t = tid; t < 512 * 16; t += 256) lsup[t] = sup[(size_t)chunk * 512 * 16 + t];
    __syncthreads();
    for (int jb = 0; jb < 8; ++jb) {
      int j = chunk * 8 + jb;          // global block index 0..15
      if (tid < 64) {
        u64 intra = lsup[(jb * 64 + lane) * 16 + j];
        u64 kw = keepres[j] & ~rem[j];
        #pragma unroll 8
        for (int bbit = 0; bbit < 64; ++bbit) {
          u64 row = __shfl(intra, bbit);
          if ((kw >> bbit) & 1ULL) kw &= ~row;
        }
        if (lane == 0) keepres[j] = kw;
      }
      __syncthreads();
      if (tid < 16) {
        u64 kw = keepres[j];
        u64 r = rem[tid];
        int base = jb * 64;
        while (kw) {
          int bbit = __ffsll(kw) - 1;
          kw &= kw - 1;
          r |= lsup[(base + bbit) * 16 + tid];
        }
        rem[tid] = r;
      }
      __syncthreads();
    }
  }
  if (tid < 16) keep[tid] = keepres[tid];
}

// ---------------- final emit: recompute pred head for kept rows ----------------
__global__ __launch_bounds__(256) void k_emit(
    const float* __restrict__ C2, const float* __restrict__ w3,
    const float* __restrict__ b3, const float* __restrict__ a3,
    const float* __restrict__ w42, const float* __restrict__ b42,
    const u64* __restrict__ selected, const u64* __restrict__ keep,
    float* __restrict__ out) {
  int r = blockIdx.x * 256 + threadIdx.x;
  if (r >= KSEL) return;
  bool kb = (keep[r >> 6] >> (r & 63)) & 1ULL;
  if (!kb) {
    out[r*5+0] = 0.0f; out[r*5+1] = 0.0f; out[r*5+2] = 0.0f;
    out[r*5+3] = 0.0f; out[r*5+4] = 0.0f;
    return;
  }
  u64 key = selected[r];
  float score = __uint_as_float(~(u32)(key >> 32));
  u32 idx = (u32)key;
  int b = (int)(idx / (u32)N3);
  int rem = (int)(idx - (u32)b * (u32)N3);
  int y = rem / W3;
  int x = rem - y * W3;
  float h[32];
  conv3_h(C2, w3, b3, a3, b, y, x, h);
  float p0 = b42[0], p1 = b42[1], p2 = b42[2], p3 = b42[3];
  #pragma unroll
  for (int c = 0; c < 32; ++c) {
    p0 = fmaf(h[c], w42[c],      p0);
    p1 = fmaf(h[c], w42[32 + c], p1);
    p2 = fmaf(h[c], w42[64 + c], p2);
    p3 = fmaf(h[c], w42[96 + c], p3);
  }
  float x1 = (float)(2 * x + 1), y1f = (float)(2 * y + 1);
  float x2 = (float)(2 * x + 12), y2f = (float)(2 * y + 12);
  float bw = x2 - x1, bh = y2f - y1f;
  float rx1 = fmaf(p0, bw, x1), ry1 = fmaf(p1, bh, y1f);
  float rx2 = fmaf(p2, bw, x2), ry2 = fmaf(p3, bh, y2f);
  float rw = rx2 - rx1, rh = ry2 - ry1;
  float l = fmaxf(rw, rh);
  float ox1 = rx1 + 0.5f * rw - 0.5f * l;
  float oy1 = ry1 + 0.5f * rh - 0.5f * l;
  out[r*5+0] = ox1; out[r*5+1] = oy1;
  out[r*5+2] = ox1 + l; out[r*5+3] = oy1 + l;
  out[r*5+4] = score;
}

extern "C" void kernel_launch(void* const* d_in, const int* in_sizes, int n_in,
                              void* d_out, int out_size, void* d_ws, size_t ws_size,
                              hipStream_t stream) {
  if (ws_size < WS_NEEDED) return;
  const float* x   = (const float*)d_in[0];
  const float* w1  = (const float*)d_in[1];
  const float* b1  = (const float*)d_in[2];
  const float* a1  = (const float*)d_in[3];
  const float* w2  = (const float*)d_in[4];
  const float* b2  = (const float*)d_in[5];
  const float* a2  = (const float*)d_in[6];
  const float* w3  = (const float*)d_in[7];
  const float* b3  = (const float*)d_in[8];
  const float* a3  = (const float*)d_in[9];
  const float* w41 = (const float*)d_in[10];
  const float* b41 = (const float*)d_in[11];
  const float* w42 = (const float*)d_in[12];
  const float* b42 = (const float*)d_in[13];

  char* ws = (char*)d_ws;
  float*  C2       = (float*)(ws + oC2);
  u64*    cands    = (u64*)(ws + oCand);
  u64*    sortbuf  = (u64*)(ws + oSort);
  u64*    selected = (u64*)(ws + oSel);
  float4* boxarr   = (float4*)(ws + oBox);
  u64*    sup      = (u64*)(ws + oSup);
  u64*    keep     = (u64*)(ws + oKeep);
  u32*    misc     = (u32*)(ws + oMisc);
  float*  out      = (float*)d_out;

  k_conv12<<<C2TX * C2TY * BATCH, 256, 0, stream>>>(x, w1, b1, a1, w2, b2, a2, C2, misc);
  k_conv3<<<C3TX * C3TY * BATCH, 256, 0, stream>>>(C2, w3, b3, a3, w41, b41, cands, misc);
  k_compact<<<512, 256, 0, stream>>>(cands, misc, sortbuf);
  k_sort<<<1, 1024, 0, stream>>>(sortbuf, misc, selected, boxarr);
  k_sup<<<64, 256, 0, stream>>>(boxarr, sup);
  k_nms<<<1, 256, 0, stream>>>(sup, misc, keep);
  k_emit<<<(KSEL + 255) / 256, 256, 0, stream>>>(C2, w3, b3, a3, w42, b42, selected, keep, out);
}

// Round 17
// 554.967 us; speedup vs baseline: 1.8450x; 1.0287x over previous
//
#include <hip/hip_runtime.h>
#include <stdint.h>

using u32 = unsigned int;
using u64 = unsigned long long;

constexpr int BATCH = 4;
constexpr int H0 = 1080, W0 = 1920;     // input
constexpr int HP = 539,  WP = 959;      // after conv1(3x3 VALID)+pool2
constexpr int H2 = 537,  W2 = 957;      // after conv2
constexpr int H3 = 535,  W3 = 955;      // after conv3
constexpr int N3 = H3 * W3;             // 510925
constexpr int TOT3 = BATCH * N3;        // 2043700
constexpr int KSEL = 1024;
constexpr int SORTCAP = 4096;
constexpr float SCORE_THR_C = 0.6f;
constexpr float IOU_THR_C = 0.5f;
constexpr float IMG_OFF = 100000.0f;

// batched grids
constexpr int C2TY = 34, C2TX = 30;     // conv12: 16x32 conv2-output tile
constexpr int C3TY = 34, C3TX = 30;     // conv3: 16x32 tile

// ---------------- workspace layout (bytes) ----------------
constexpr size_t align256(size_t x) { return (x + 255) & ~(size_t)255; }
constexpr size_t oC2   = 0;
constexpr size_t sC2   = (size_t)BATCH * 16 * H2 * W2 * 4;     // 131.5 MB
constexpr size_t oCand = align256(oC2 + sC2);
constexpr size_t sCand = (size_t)TOT3 * 8;                     // 16.3 MB
constexpr size_t oSort = align256(oCand + sCand);
constexpr size_t oSel  = align256(oSort + (size_t)SORTCAP * 8);
constexpr size_t oBox  = align256(oSel + (size_t)KSEL * 8);
constexpr size_t oSup  = align256(oBox + (size_t)KSEL * 16);
constexpr size_t oKeep = align256(oSup + (size_t)KSEL * 16 * 8);
constexpr size_t oMisc = align256(oKeep + 16 * 8);
constexpr int    MISC_WORDS = 16 + 2048;   // [0]=cand_count [1]=sel_count [2]=bstar [3]=keff ; +16: hist[2048]
constexpr size_t WS_NEEDED = oMisc + (size_t)MISC_WORDS * 4;

__device__ __forceinline__ int keybin(u64 key) {
  u32 khi = (u32)(key >> 32);
  int d = (int)(khi - 0xC0800000u);   // scores in [0.5,1) land in [0, 0x800000)
  if (d < 0) d = 0;
  int bin = d >> 12;
  return bin > 2047 ? 2047 : bin;
}

// ---------------- fused conv1+pool+conv2 : one 16x32 conv2-output tile per block ----------------
// Phase A (strength-reduced staging): stage x tile 3ci x 38 x 70 (stride 71).
// Phase B: conv1+PReLU+pool to registers (1 pooled px x 10 ch per task, 612 px).
// Phase C: conv2 (measured-best body) reading p1t overwritten onto the dead x region.
__global__ __launch_bounds__(256) void k_conv12(
    const float* __restrict__ x, const float* __restrict__ w1,
    const float* __restrict__ b1, const float* __restrict__ a1,
    const float* __restrict__ w2, const float* __restrict__ b2,
    const float* __restrict__ a2,
    float* __restrict__ C2, u32* __restrict__ misc) {
  __shared__ float sm[8094];     // max(x tile 8094, p1t 6300)
  int tid = threadIdx.x;
  int blk = blockIdx.x;
  if (blk == 0) {
    for (int i = tid; i < MISC_WORDS; i += 256) misc[i] = 0;
  }
  int tx = blk % C2TX; int r1 = blk / C2TX; int ty = r1 % C2TY; int b = r1 / C2TY;
  int r0 = 16 * ty; if (r0 > 521) r0 = 521;    // clamp; overlap recompute idempotent
  int c0 = 32 * tx; if (c0 > 925) c0 = 925;

  // phase A: stage x rows 2r0..2r0+37, cols 2c0..2c0+69, 3 ci
  // slot-outer/ci-inner: 11 divisions total (was ~64), constant-offset plane hops
  const float* xb = x + (size_t)b * 3 * H0 * W0 + (size_t)(2 * r0) * W0 + (2 * c0);
  #pragma unroll
  for (int s = 0; s < 11; ++s) {
    int p = tid + s * 256;
    if (s < 10 || tid < 100) {   // p < 2660
      int row = p / 70, col = p - row * 70;
      const float* g = xb + (size_t)row * W0 + col;
      float* sp = sm + row * 71 + col;
      sp[0]        = g[0];
      sp[2698]     = g[(size_t)H0 * W0];
      sp[2 * 2698] = g[(size_t)(2 * H0) * W0];
    }
  }
  __syncthreads();

  // phase B: conv1 + PReLU + pool for the 18x34 pooled halo, into registers
  float pool[3][10];
  #pragma unroll
  for (int it = 0; it < 3; ++it) {
    int p = tid + it * 256;
    if (p < 612) {
      int py = p / 34, pxc = p - py * 34;
      float accv[10][4];
      #pragma unroll
      for (int c = 0; c < 10; ++c) {
        float bb = b1[c];
        accv[c][0] = bb; accv[c][1] = bb; accv[c][2] = bb; accv[c][3] = bb;
      }
      #pragma unroll 1
      for (int ci = 0; ci < 3; ++ci) {
        const float* sp = sm + ci * 2698 + (2 * py) * 71 + 2 * pxc;
        float in[4][4];
        #pragma unroll
        for (int dy = 0; dy < 4; ++dy)
          #pragma unroll
          for (int dx = 0; dx < 4; ++dx)
            in[dy][dx] = sp[dy * 71 + dx];
        #pragma unroll
        for (int c = 0; c < 10; ++c) {
          const float* wc = w1 + (c * 3 + ci) * 9;
          float w0v = wc[0], w1v = wc[1], w2v = wc[2], w3v = wc[3], w4v = wc[4],
                w5v = wc[5], w6v = wc[6], w7v = wc[7], w8v = wc[8];
          #pragma unroll
          for (int sy = 0; sy < 2; ++sy)
            #pragma unroll
            for (int sx = 0; sx < 2; ++sx) {
              float a = accv[c][sy * 2 + sx];
              a = fmaf(in[sy][sx],     w0v, a); a = fmaf(in[sy][sx+1],   w1v, a); a = fmaf(in[sy][sx+2],   w2v, a);
              a = fmaf(in[sy+1][sx],   w3v, a); a = fmaf(in[sy+1][sx+1], w4v, a); a = fmaf(in[sy+1][sx+2], w5v, a);
              a = fmaf(in[sy+2][sx],   w6v, a); a = fmaf(in[sy+2][sx+1], w7v, a); a = fmaf(in[sy+2][sx+2], w8v, a);
              accv[c][sy * 2 + sx] = a;
            }
        }
      }
      #pragma unroll
      for (int c = 0; c < 10; ++c) {
        float al = a1[c];
        float v0 = accv[c][0] >= 0.0f ? accv[c][0] : al * accv[c][0];
        float v1 = accv[c][1] >= 0.0f ? accv[c][1] : al * accv[c][1];
        float v2 = accv[c][2] >= 0.0f ? accv[c][2] : al * accv[c][2];
        float v3 = accv[c][3] >= 0.0f ? accv[c][3] : al * accv[c][3];
        pool[it][c] = fmaxf(fmaxf(v0, v1), fmaxf(v2, v3));
      }
    }
  }
  __syncthreads();   // all x-tile reads complete

  // write p1t over the dead x region: p1t[c][py][pxc], stride 35
  #pragma unroll
  for (int it = 0; it < 3; ++it) {
    int p = tid + it * 256;
    if (p < 612) {
      int py = p / 34, pxc = p - py * 34;
      float* sp = sm + py * 35 + pxc;
      #pragma unroll
      for (int c = 0; c < 10; ++c)
        sp[c * 630] = pool[it][c];
    }
  }
  __syncthreads();

  // phase C: conv2 + PReLU (measured-best body)
  int lane = tid & 63;
  int wv = __builtin_amdgcn_readfirstlane(tid >> 6);
  int c_lo = wv * 4;
  int rr = lane >> 3;      // row-pair 0..7
  int gg = lane & 7;       // col-group 0..7

  float acc[4][8];         // [c][d*4 + k]
  #pragma unroll
  for (int c = 0; c < 4; ++c) {
    float bb = b2[c_lo + c];
    #pragma unroll
    for (int o = 0; o < 8; ++o) acc[c][o] = bb;
  }
  #pragma unroll 1
  for (int ci = 0; ci < 10; ++ci) {
    const float* sp = sm + ci * 630 + (2 * rr) * 35 + 4 * gg;
    float in[4][6];
    #pragma unroll
    for (int dy = 0; dy < 4; ++dy)
      #pragma unroll
      for (int dx = 0; dx < 6; ++dx)
        in[dy][dx] = sp[dy * 35 + dx];
    #pragma unroll
    for (int c = 0; c < 4; ++c) {
      const float* wc = w2 + ((c_lo + c) * 10 + ci) * 9;
      float w0v = wc[0], w1v = wc[1], w2v = wc[2], w3v = wc[3], w4v = wc[4],
            w5v = wc[5], w6v = wc[6], w7v = wc[7], w8v = wc[8];
      #pragma unroll
      for (int d = 0; d < 2; ++d)
        #pragma unroll
        for (int k = 0; k < 4; ++k) {
          float a = acc[c][d * 4 + k];
          a = fmaf(in[d][k],   w0v, a); a = fmaf(in[d][k+1],   w1v, a); a = fmaf(in[d][k+2],   w2v, a);
          a = fmaf(in[d+1][k], w3v, a); a = fmaf(in[d+1][k+1], w4v, a); a = fmaf(in[d+1][k+2], w5v, a);
          a = fmaf(in[d+2][k], w6v, a); a = fmaf(in[d+2][k+1], w7v, a); a = fmaf(in[d+2][k+2], w8v, a);
          acc[c][d * 4 + k] = a;
        }
    }
  }
  #pragma unroll
  for (int c = 0; c < 4; ++c) {
    float al = a2[c_lo + c];
    #pragma unroll
    for (int d = 0; d < 2; ++d) {
      int gy = r0 + 2 * rr + d;
      size_t base = ((size_t)(b * 16 + c_lo + c) * H2 + gy) * W2 + (c0 + 4 * gg);
      #pragma unroll
      for (int k = 0; k < 4; ++k) {
        float v = acc[c][d * 4 + k];
        C2[base + k] = v >= 0.0f ? v : al * v;
      }
    }
  }
}

// ---------------- conv3 core (scalar 32-ch; used by k_emit only) ----------------
__device__ __forceinline__ void conv3_h(
    const float* __restrict__ C2, const float* __restrict__ w3,
    const float* __restrict__ b3, const float* __restrict__ a3,
    int b, int y, int x, float* h) {
  #pragma unroll
  for (int c = 0; c < 32; ++c) h[c] = b3[c];
  #pragma unroll 1
  for (int ci = 0; ci < 16; ++ci) {
    const float* p = C2 + ((size_t)(b * 16 + ci) * H2 + y) * W2 + x;
    float i0 = p[0],      i1 = p[1],      i2 = p[2];
    float i3 = p[W2],     i4 = p[W2+1],   i5 = p[W2+2];
    float i6 = p[2*W2],   i7 = p[2*W2+1], i8 = p[2*W2+2];
    const float* wp = w3 + ci * 9;
    #pragma unroll
    for (int c = 0; c < 32; ++c) {
      const float* wc = wp + c * 144;
      h[c] = fmaf(i0, wc[0], h[c]); h[c] = fmaf(i1, wc[1], h[c]);
      h[c] = fmaf(i2, wc[2], h[c]); h[c] = fmaf(i3, wc[3], h[c]);
      h[c] = fmaf(i4, wc[4], h[c]); h[c] = fmaf(i5, wc[5], h[c]);
      h[c] = fmaf(i6, wc[6], h[c]); h[c] = fmaf(i7, wc[7], h[c]);
      h[c] = fmaf(i8, wc[8], h[c]);
    }
  }
  #pragma unroll
  for (int c = 0; c < 32; ++c) h[c] = h[c] >= 0.0f ? h[c] : a3[c] * h[c];
}

// ---------------- conv3 + PReLU + head + filter + inline hist : tile 16x32, 4 waves x 8 ch, 8 px/thread ----------------
// Strength-reduced staging: 3 divisions/thread (was ~76), ci-plane hops via constant offsets.
__global__ __launch_bounds__(256) void k_conv3(
    const float* __restrict__ C2, const float* __restrict__ w3,
    const float* __restrict__ b3, const float* __restrict__ a3,
    const float* __restrict__ w41, const float* __restrict__ b41,
    u64* __restrict__ cands, u32* __restrict__ misc) {
  __shared__ __align__(16) float sm[10080];
  int tid = threadIdx.x;
  int blk = blockIdx.x;
  int tx = blk % C3TX; int r1 = blk / C3TX; int ty = r1 % C3TY; int b = r1 / C3TY;
  int ymin = 16 * ty, xmin = 32 * tx;
  int r0 = ymin > 519 ? 519 : ymin;
  int c0 = xmin > 923 ? 923 : xmin;

  // phase A: stage 16ci x 18 x 34 input tile (row stride 35); 612 px per plane, 3 slots
  {
    const float* Cb = C2 + (size_t)b * 16 * H2 * W2 + (size_t)r0 * W2 + c0;
    int pA = tid;        int rA = pA / 34, cA = pA - rA * 34;
    int pB = tid + 256;  int rB = pB / 34, cB = pB - rB * 34;
    int pC = tid + 512;  int rC = pC / 34, cC = pC - rC * 34;
    const float* gA = Cb + (size_t)rA * W2 + cA;
    const float* gB = Cb + (size_t)rB * W2 + cB;
    const float* gC = Cb + (size_t)rC * W2 + cC;
    float* sA = sm + rA * 35 + cA;
    float* sB = sm + rB * 35 + cB;
    float* sC = sm + rC * 35 + cC;
    bool hasC = tid < 100;   // 612 - 512
    #pragma unroll 1
    for (int ci = 0; ci < 16; ++ci) {
      sA[0] = gA[0];
      sB[0] = gB[0];
      if (hasC) sC[0] = gC[0];
      gA += (size_t)H2 * W2; gB += (size_t)H2 * W2; gC += (size_t)H2 * W2;
      sA += 630; sB += 630; sC += 630;
    }
  }
  __syncthreads();

  // phase B: conv + PReLU. wave wv: channels 8wv..8wv+7; thread: rows 2rr..2rr+1, cols 4gg..4gg+3
  int lane = tid & 63;
  int wv = __builtin_amdgcn_readfirstlane(tid >> 6);
  int c_lo = wv * 8;
  int rr = lane >> 3;      // row-pair 0..7
  int gg = lane & 7;       // col-group 0..7

  float acc[8][8];         // [c][drow*4 + k]
  #pragma unroll
  for (int c = 0; c < 8; ++c) {
    float bb = b3[c_lo + c];
    #pragma unroll
    for (int o = 0; o < 8; ++o) acc[c][o] = bb;
  }
  #pragma unroll 1
  for (int ci = 0; ci < 16; ++ci) {
    const float* sp = sm + ci * 630 + (2 * rr) * 35 + 4 * gg;
    float in[4][6];
    #pragma unroll
    for (int dy = 0; dy < 4; ++dy)
      #pragma unroll
      for (int dx = 0; dx < 6; ++dx)
        in[dy][dx] = sp[dy * 35 + dx];
    #pragma unroll
    for (int c = 0; c < 8; ++c) {
      const float* wc = w3 + ((c_lo + c) * 16 + ci) * 9;
      float w0v = wc[0], w1v = wc[1], w2v = wc[2], w3v = wc[3], w4v = wc[4],
            w5v = wc[5], w6v = wc[6], w7v = wc[7], w8v = wc[8];
      #pragma unroll
      for (int d = 0; d < 2; ++d)
        #pragma unroll
        for (int k = 0; k < 4; ++k) {
          float a = acc[c][d * 4 + k];
          a = fmaf(in[d][k],   w0v, a); a = fmaf(in[d][k+1],   w1v, a); a = fmaf(in[d][k+2],   w2v, a);
          a = fmaf(in[d+1][k], w3v, a); a = fmaf(in[d+1][k+1], w4v, a); a = fmaf(in[d+1][k+2], w5v, a);
          a = fmaf(in[d+2][k], w6v, a); a = fmaf(in[d+2][k+1], w7v, a); a = fmaf(in[d+2][k+2], w8v, a);
          acc[c][d * 4 + k] = a;
        }
    }
  }
  #pragma unroll
  for (int c = 0; c < 8; ++c) {
    float al = a3[c_lo + c];
    #pragma unroll
    for (int o = 0; o < 8; ++o) {
      float v = acc[c][o];
      acc[c][o] = v >= 0.0f ? v : al * v;
    }
  }
  __syncthreads();   // input tile dead

  // phases C1/D1 then C2/D2: h-exchange + head, one 8-row half at a time (h[32][256] = 32 KB)
  #pragma unroll
  for (int halfp = 0; halfp < 2; ++halfp) {
    if ((rr >> 2) == halfp) {
      #pragma unroll
      for (int c = 0; c < 8; ++c)
        #pragma unroll
        for (int d = 0; d < 2; ++d) {
          int row = 2 * rr + d - 8 * halfp;    // 0..7 within half
          int word = (c_lo + c) * 256 + row * 32 + 4 * gg;
          *(float4*)&sm[word] = make_float4(acc[c][d*4+0], acc[c][d*4+1], acc[c][d*4+2], acc[c][d*4+3]);
        }
    }
    __syncthreads();
    {
      int p = tid;
      float l0 = b41[0], l1 = b41[1];
      #pragma unroll
      for (int c = 0; c < 32; ++c) {
        float hv = sm[c * 256 + p];
        l0 = fmaf(hv, w41[c],      l0);
        l1 = fmaf(hv, w41[32 + c], l1);
      }
      float prob = 1.0f / (1.0f + expf(l0 - l1));   // softmax[:,1] == sigmoid(l1-l0)
      int gy = r0 + 8 * halfp + (p >> 5);
      int gx = c0 + (p & 31);
      if (prob >= SCORE_THR_C && gy >= ymin && gx >= xmin) {
        u32 idx = (u32)(b * N3 + gy * W3 + gx);
        u64 key = ((u64)(~__float_as_uint(prob)) << 32) | idx;
        atomicAdd(&misc[16 + keybin(key)], 1u);     // inline histogram
        u32 pos = atomicAdd(&misc[0], 1u);
        cands[pos] = key;
      }
    }
    __syncthreads();
  }
}

// ---------------- top-k: compact with fused scan (each block derives bstar locally) ----------------
__global__ __launch_bounds__(256) void k_compact(const u64* __restrict__ cands,
                                                u32* __restrict__ misc,
                                                u64* __restrict__ sortbuf) {
  __shared__ u32 lh[2048];
  __shared__ u32 part[256];
  __shared__ u32 sb;
  int tid = threadIdx.x;
  const u32* hist = misc + 16;
  for (int t = tid; t < 2048; t += 256) lh[t] = hist[t];
  __syncthreads();
  u32 s = 0;
  #pragma unroll
  for (int k = 0; k < 8; ++k) s += lh[tid * 8 + k];
  part[tid] = s;
  __syncthreads();
  if (tid == 0) {
    u32 total = misc[0]; if (total > (u32)TOT3) total = TOT3;
    u32 keff = total < (u32)KSEL ? total : (u32)KSEL;
    u32 run = 0; int chunk = 255;
    for (int t = 0; t < 256; ++t) {
      if (run + part[t] >= keff) { chunk = t; break; }
      run += part[t];
    }
    int bstar = 2047;
    for (int b = chunk * 8; b < chunk * 8 + 8; ++b) {
      u32 hv = lh[b];
      if (run + hv >= keff) { bstar = b; break; }
      run += hv;
    }
    sb = (u32)bstar;
    if (blockIdx.x == 0) { misc[2] = (u32)bstar; misc[3] = keff; }   // for k_nms
  }
  __syncthreads();
  int bstar = (int)sb;
  u32 n = misc[0]; if (n > (u32)TOT3) n = TOT3;
  u32 stride = gridDim.x * 256;
  for (u32 i = blockIdx.x * 256 + tid; i < n; i += stride) {
    u64 key = cands[i];
    if (keybin(key) <= bstar) {
      u32 pos = atomicAdd(&misc[1], 1u);
      if (pos < (u32)SORTCAP) sortbuf[pos] = key;
    }
  }
}

// bitonic sort (adaptive pow2 size >= nsel) in LDS; emit sorted top-1024 keys + NMS boxes
__global__ __launch_bounds__(1024) void k_sort(const u64* __restrict__ sortbuf,
                                               const u32* __restrict__ misc,
                                               u64* __restrict__ selected,
                                               float4* __restrict__ boxarr) {
  __shared__ u64 s[SORTCAP];
  int tid = threadIdx.x;
  u32 nsel = misc[1]; if (nsel > (u32)SORTCAP) nsel = SORTCAP;
  unsigned m = KSEL;
  while (m < nsel) m <<= 1;              // uniform across block
  for (int t = tid; t < (int)m; t += 1024) s[t] = (t < (int)nsel) ? sortbuf[t] : ~0ULL;
  for (unsigned k = 2; k <= m; k <<= 1) {
    for (unsigned j = k >> 1; j > 0; j >>= 1) {
      __syncthreads();
      for (int t = tid; t < (int)m; t += 1024) {
        int ixj = t ^ (int)j;
        if (ixj > t) {
          u64 a = s[t], b = s[ixj];
          bool up = ((t & (int)k) == 0);
          if ((a > b) == up) { s[t] = b; s[ixj] = a; }
        }
      }
    }
  }
  __syncthreads();
  if (tid < KSEL) {
    u64 key = s[tid];
    selected[tid] = key;
    u32 idx = (u32)key;
    u32 b = idx / (u32)N3;
    u32 rem = idx - b * (u32)N3;
    u32 y = rem / (u32)W3;
    u32 x = rem - y * (u32)W3;
    float off = (float)b * IMG_OFF;
    float x1 = (float)(2 * (int)x + 1) + off;
    float y1 = (float)(2 * (int)y + 1) + off;
    boxarr[tid] = make_float4(x1, y1, x1 + 11.0f, y1 + 11.0f);
  }
}

// ---------------- NMS: suppression bitmask matrix ----------------
__global__ __launch_bounds__(256) void k_sup(const float4* __restrict__ boxarr,
                                             u64* __restrict__ sup) {
  __shared__ float4 lbox[KSEL];
  int tid = threadIdx.x;
  for (int t = tid; t < KSEL; t += 256) lbox[t] = boxarr[t];
  __syncthreads();
  int i = blockIdx.x * 16 + (tid >> 4);
  int w = tid & 15;
  float4 bi = lbox[i];
  float ai = (bi.z - bi.x) * (bi.w - bi.y);
  u64 m = 0;
  #pragma unroll 4
  for (int jj = 0; jj < 64; ++jj) {
    int j = (w << 6) + jj;
    float4 bj = lbox[j];
    float xx1 = fmaxf(bi.x, bj.x), yy1 = fmaxf(bi.y, bj.y);
    float xx2 = fminf(bi.z, bj.z), yy2 = fminf(bi.w, bj.w);
    float inter = fmaxf(xx2 - xx1, 0.0f) * fmaxf(yy2 - yy1, 0.0f);
    float aj = (bj.z - bj.x) * (bj.w - bj.y);
    float iou = inter / (ai + aj - inter);
    if (iou > IOU_THR_C && j > i) m |= (1ULL << jj);
  }
  sup[(size_t)i * 16 + w] = m;
}

// block-parallel greedy NMS: 16 column-blocks of 64, wave-uniform intra-block bit loop.
__global__ __launch_bounds__(256) void k_nms(const u64* __restrict__ sup,
                                             const u32* __restrict__ misc,
                                             u64* __restrict__ keep) {
  __shared__ u64 lsup[512 * 16];    // 64 KB (rows of one chunk)
  __shared__ u64 rem[16];           // accumulated suppression from accepted boxes
  __shared__ u64 keepres[16];
  int tid = threadIdx.x;
  int lane = tid & 63;
  int total = (int)misc[3];
  if (tid < 16) {
    rem[tid] = 0;
    int nb = total - tid * 64;
    keepres[tid] = nb >= 64 ? ~0ULL : (nb <= 0 ? 0ULL : ((1ULL << nb) - 1ULL));
  }
  for (int chunk = 0; chunk < 2; ++chunk) {
    for (int t = tid; t < 512 * 16; t += 256) lsup[t] = sup[(size_t)chunk * 512 * 16 + t];
    __syncthreads();
    for (int jb = 0; jb < 8; ++jb) {
      int j = chunk * 8 + jb;          // global block index 0..15
      if (tid < 64) {
        u64 intra = lsup[(jb * 64 + lane) * 16 + j];
        u64 kw = keepres[j] & ~rem[j];
        #pragma unroll 8
        for (int bbit = 0; bbit < 64; ++bbit) {
          u64 row = __shfl(intra, bbit);
          if ((kw >> bbit) & 1ULL) kw &= ~row;
        }
        if (lane == 0) keepres[j] = kw;
      }
      __syncthreads();
      if (tid < 16) {
        u64 kw = keepres[j];
        u64 r = rem[tid];
        int base = jb * 64;
        while (kw) {
          int bbit = __ffsll(kw) - 1;
          kw &= kw - 1;
          r |= lsup[(base + bbit) * 16 + tid];
        }
        rem[tid] = r;
      }
      __syncthreads();
    }
  }
  if (tid < 16) keep[tid] = keepres[tid];
}

// ---------------- final emit: recompute pred head for kept rows ----------------
__global__ __launch_bounds__(256) void k_emit(
    const float* __restrict__ C2, const float* __restrict__ w3,
    const float* __restrict__ b3, const float* __restrict__ a3,
    const float* __restrict__ w42, const float* __restrict__ b42,
    const u64* __restrict__ selected, const u64* __restrict__ keep,
    float* __restrict__ out) {
  int r = blockIdx.x * 256 + threadIdx.x;
  if (r >= KSEL) return;
  bool kb = (keep[r >> 6] >> (r & 63)) & 1ULL;
  if (!kb) {
    out[r*5+0] = 0.0f; out[r*5+1] = 0.0f; out[r*5+2] = 0.0f;
    out[r*5+3] = 0.0f; out[r*5+4] = 0.0f;
    return;
  }
  u64 key = selected[r];
  float score = __uint_as_float(~(u32)(key >> 32));
  u32 idx = (u32)key;
  int b = (int)(idx / (u32)N3);
  int rem = (int)(idx - (u32)b * (u32)N3);
  int y = rem / W3;
  int x = rem - y * W3;
  float h[32];
  conv3_h(C2, w3, b3, a3, b, y, x, h);
  float p0 = b42[0], p1 = b42[1], p2 = b42[2], p3 = b42[3];
  #pragma unroll
  for (int c = 0; c < 32; ++c) {
    p0 = fmaf(h[c], w42[c],      p0);
    p1 = fmaf(h[c], w42[32 + c], p1);
    p2 = fmaf(h[c], w42[64 + c], p2);
    p3 = fmaf(h[c], w42[96 + c], p3);
  }
  float x1 = (float)(2 * x + 1), y1f = (float)(2 * y + 1);
  float x2 = (float)(2 * x + 12), y2f = (float)(2 * y + 12);
  float bw = x2 - x1, bh = y2f - y1f;
  float rx1 = fmaf(p0, bw, x1), ry1 = fmaf(p1, bh, y1f);
  float rx2 = fmaf(p2, bw, x2), ry2 = fmaf(p3, bh, y2f);
  float rw = rx2 - rx1, rh = ry2 - ry1;
  float l = fmaxf(rw, rh);
  float ox1 = rx1 + 0.5f * rw - 0.5f * l;
  float oy1 = ry1 + 0.5f * rh - 0.5f * l;
  out[r*5+0] = ox1; out[r*5+1] = oy1;
  out[r*5+2] = ox1 + l; out[r*5+3] = oy1 + l;
  out[r*5+4] = score;
}

extern "C" void kernel_launch(void* const* d_in, const int* in_sizes, int n_in,
                              void* d_out, int out_size, void* d_ws, size_t ws_size,
                              hipStream_t stream) {
  if (ws_size < WS_NEEDED) return;
  const float* x   = (const float*)d_in[0];
  const float* w1  = (const float*)d_in[1];
  const float* b1  = (const float*)d_in[2];
  const float* a1  = (const float*)d_in[3];
  const float* w2  = (const float*)d_in[4];
  const float* b2  = (const float*)d_in[5];
  const float* a2  = (const float*)d_in[6];
  const float* w3  = (const float*)d_in[7];
  const float* b3  = (const float*)d_in[8];
  const float* a3  = (const float*)d_in[9];
  const float* w41 = (const float*)d_in[10];
  const float* b41 = (const float*)d_in[11];
  const float* w42 = (const float*)d_in[12];
  const float* b42 = (const float*)d_in[13];

  char* ws = (char*)d_ws;
  float*  C2       = (float*)(ws + oC2);
  u64*    cands    = (u64*)(ws + oCand);
  u64*    sortbuf  = (u64*)(ws + oSort);
  u64*    selected = (u64*)(ws + oSel);
  float4* boxarr   = (float4*)(ws + oBox);
  u64*    sup      = (u64*)(ws + oSup);
  u64*    keep     = (u64*)(ws + oKeep);
  u32*    misc     = (u32*)(ws + oMisc);
  float*  out      = (float*)d_out;

  k_conv12<<<C2TX * C2TY * BATCH, 256, 0, stream>>>(x, w1, b1, a1, w2, b2, a2, C2, misc);
  k_conv3<<<C3TX * C3TY * BATCH, 256, 0, stream>>>(C2, w3, b3, a3, w41, b41, cands, misc);
  k_compact<<<512, 256, 0, stream>>>(cands, misc, sortbuf);
  k_sort<<<1, 1024, 0, stream>>>(sortbuf, misc, selected, boxarr);
  k_sup<<<64, 256, 0, stream>>>(boxarr, sup);
  k_nms<<<1, 256, 0, stream>>>(sup, misc, keep);
  k_emit<<<(KSEL + 255) / 256, 256, 0, stream>>>(C2, w3, b3, a3, w42, b42, selected, keep, out);
}